// Round 13
// baseline (331.312 us; speedup 1.0000x reference)
//
#include <hip/hip_runtime.h>
#include <math.h>

#define EPS_LN 1e-5f

#define B_  2
#define ST_ 2048
#define SI_ 1024
#define K_  64
#define D_  768
#define E_  256

typedef __bf16 bf16x8 __attribute__((ext_vector_type(8)));
typedef float  f32x4  __attribute__((ext_vector_type(4)));
typedef unsigned short ushort_t;

__device__ inline ushort_t f2bf(float x) {
    unsigned int u = __float_as_uint(x);
    unsigned int r = (u + 0x7FFFu + ((u >> 16) & 1u)) >> 16;
    return (ushort_t)r;
}

// ===========================================================================
// Device bodies for fused kernels
// ===========================================================================

__device__ void ln_stats_body(int bid, int tid,
    const float* __restrict__ xt, const float* __restrict__ xi,
    const float* __restrict__ xl, float* __restrict__ mu, float* __restrict__ rstd)
{
    int w = tid >> 6, lane = tid & 63;
    int row = bid * 4 + w;
    const float* src;
    if (row < 4096) src = xt + (size_t)row * D_;
    else if (row < 6144) src = xi + (size_t)(row - 4096) * D_;
    else src = xl + (size_t)(row - 6144) * D_;
    float s = 0.f, q = 0.f;
    #pragma unroll
    for (int rep = 0; rep < 3; ++rep) {
        float4 v = *(const float4*)(src + lane * 4 + rep * 256);
        s += v.x + v.y + v.z + v.w;
        q += v.x * v.x + v.y * v.y + v.z * v.z + v.w * v.w;
    }
    #pragma unroll
    for (int off = 32; off > 0; off >>= 1) {
        s += __shfl_xor(s, off, 64);
        q += __shfl_xor(q, off, 64);
    }
    if (lane == 0) {
        float m = s / (float)D_;
        float var = q / (float)D_ - m * m;
        mu[row] = m;
        rstd[row] = rsqrtf(var + EPS_LN);
    }
}

__device__ void sgemm_body(char* smem, int tid,
    const float* __restrict__ A, const float* __restrict__ Bm,
    const float* __restrict__ rowScale, const float* __restrict__ bias,
    const float* __restrict__ muA, const float* __restrict__ sdA, int so,
    float* __restrict__ C, int kz, int bx, int by, int Kd, int N)
{
    float (*As)[65] = (float(*)[65])smem;
    float (*Bs)[64] = (float(*)[64])(smem + 16 * 65 * 4);
    int tx = tid & 15, ty = tid >> 4;
    int row0 = by * 64;
    int col0 = bx * 64;
    float acc[4][4] = {};
    int kbase = kz * 128;
    for (int k0 = kbase; k0 < kbase + 128; k0 += 16) {
        {
            int e = tid * 4;
            int r = e >> 4, kk = e & 15;
            float4 av = *(const float4*)(A + (size_t)(row0 + r) * Kd + k0 + kk);
            if (muA) {
                float m = muA[so + row0 + r], sd = sdA[so + row0 + r];
                av.x = (av.x - m) * sd; av.y = (av.y - m) * sd;
                av.z = (av.z - m) * sd; av.w = (av.w - m) * sd;
            }
            As[kk + 0][r] = av.x; As[kk + 1][r] = av.y; As[kk + 2][r] = av.z; As[kk + 3][r] = av.w;
        }
        {
            int e = tid * 4;
            int kk = e >> 6, c = e & 63;
            float4 bv = *(const float4*)(Bm + (size_t)(k0 + kk) * N + col0 + c);
            if (rowScale) {
                float sc = rowScale[k0 + kk];
                bv.x *= sc; bv.y *= sc; bv.z *= sc; bv.w *= sc;
            }
            *(float4*)&Bs[kk][c] = bv;
        }
        __syncthreads();
        #pragma unroll
        for (int kk = 0; kk < 16; ++kk) {
            float a[4], b[4];
            #pragma unroll
            for (int i = 0; i < 4; ++i) a[i] = As[kk][ty + 16 * i];
            #pragma unroll
            for (int j = 0; j < 4; ++j) b[j] = Bs[kk][tx + 16 * j];
            #pragma unroll
            for (int i = 0; i < 4; ++i)
                #pragma unroll
                for (int j = 0; j < 4; ++j)
                    acc[i][j] += a[i] * b[j];
        }
        __syncthreads();
    }
    #pragma unroll
    for (int i = 0; i < 4; ++i) {
        int r = row0 + ty + 16 * i;
        #pragma unroll
        for (int j = 0; j < 4; ++j) {
            int c = col0 + tx + 16 * j;
            float v = acc[i][j];
            if (kz == 0 && bias) v += bias[c];
            atomicAdd(&C[(size_t)r * N + c], v);
        }
    }
}

// ===========================================================================
// prelude: ln_stats (1568) + fold_all (864) + packB2 (192) = 2624 blocks
// dyn LDS: 1024 B
// ===========================================================================
__global__ __launch_bounds__(256) void prelude_kernel(
    const float* __restrict__ xt, const float* __restrict__ xi,
    const float* __restrict__ xl, float* __restrict__ mu, float* __restrict__ rstd,
    const float* b0, const float* W0, const float* w0, float* f0,
    const float* b1, const float* W1, const float* w1, float* f1,
    const float* b2, const float* W2, const float* w2, float* f2,
    const float* b3, const float* W3, const float* w3, float* f3,
    const float* b4, const float* W4, const float* w4, float* f4,
    const float* b5, const float* W5, const float* w5, float* f5,
    const float* __restrict__ Wsu_t, const float* __restrict__ g_t, ushort_t* __restrict__ WF_t,
    const float* __restrict__ Wsu_i, const float* __restrict__ g_i, ushort_t* __restrict__ WF_i)
{
    extern __shared__ __align__(16) char smem[];
    int bid = blockIdx.x;
    int tid = threadIdx.x;
    if (bid < 1568) {
        ln_stats_body(bid, tid, xt, xi, xl, mu, rstd);
        return;
    }
    if (bid < 2432) {
        // fold_all
        int f = bid - 1568;
        int ebx = f % 12, dby = (f / 12) % 12, cfg = f / 144;
        const float* blns[6] = {b0, b1, b2, b3, b4, b5};
        const float* Ws[6]   = {W0, W1, W2, W3, W4, W5};
        const float* wbs[6]  = {w0, w1, w2, w3, w4, w5};
        float* bfs[6]        = {f0, f1, f2, f3, f4, f5};
        int E = (cfg >= 4) ? 768 : 256;
        if (ebx * 64 >= E) return;
        const float* bln = blns[cfg];
        const float* W = Ws[cfg];
        float (*red)[64] = (float(*)[64])smem;
        int c = tid & 63, part = tid >> 6;
        int e = ebx * 64 + c;
        int d0 = dby * 64;
        float s = 0.f;
        #pragma unroll
        for (int i = 0; i < 16; ++i) {
            int d = d0 + part * 16 + i;
            s += bln[d] * W[(size_t)d * E + e];
        }
        red[part][c] = s; __syncthreads();
        if (part == 0) {
            float v = red[0][c] + red[1][c] + red[2][c] + red[3][c];
            if (dby == 0 && wbs[cfg]) v += wbs[cfg][e];
            atomicAdd(&bfs[cfg][e], v);
        }
        return;
    }
    // packB2
    {
        const int HALF = (D_ >> 5) * (E_ >> 4) * 64;  // 24576
        int gidx = (bid - 2432) * 256 + tid;
        int isImg = gidx >= HALF;
        int idx = isImg ? gidx - HALF : gidx;
        const float* W = isImg ? Wsu_i : Wsu_t;
        const float* g = isImg ? g_i : g_t;
        ushort_t* out = isImg ? WF_i : WF_t;
        int lane = idx & 63;
        int ntile = (idx >> 6) & 15;
        int c = idx >> 10;
        int n = ntile * 16 + (lane & 15);
        int k0 = c * 32 + (lane >> 4) * 8;
        ushort_t o[8];
        #pragma unroll
        for (int j = 0; j < 8; ++j) {
            int k = k0 + j;
            o[j] = f2bf(W[(size_t)k * E_ + n] * g[k]);
        }
        *reinterpret_cast<uint4*>(out + (size_t)idx * 8) = *reinterpret_cast<uint4*>(o);
    }
}

// ===========================================================================
// stage2: tpack (1152) + t-proj sgemm (96) = 1248 blocks. dyn LDS 17152 B
// ===========================================================================
__global__ __launch_bounds__(256) void stage2_kernel(
    const float* __restrict__ xt, const float* __restrict__ xi,
    const float* __restrict__ mu, const float* __restrict__ rstd,
    ushort_t* __restrict__ XrF_t, ushort_t* __restrict__ XhF_t, ushort_t* __restrict__ AF_t,
    ushort_t* __restrict__ XrF_i, ushort_t* __restrict__ XhF_i, ushort_t* __restrict__ AF_i,
    const float* __restrict__ lat,
    const float* __restrict__ t_tp_w, const float* __restrict__ t_tn_g,
    const float* __restrict__ b_tp_t, float* __restrict__ t_t,
    const float* __restrict__ i_tp_w, const float* __restrict__ i_tn_g,
    const float* __restrict__ b_tp_i, float* __restrict__ t_i)
{
    extern __shared__ __align__(16) char smem[];
    int bid = blockIdx.x;
    int t = threadIdx.x;
    if (bid < 1152) {
        // tpack
        int bx = bid % 96, by = bid / 96;
        float (*tile)[65] = (float(*)[65])smem;
        float* mu_s = (float*)(smem + 64 * 65 * 4);
        float* rs_s = mu_s + 64;
        int isImg = bx >= 64;
        const float* x = isImg ? xi : xt;
        ushort_t* XrF = isImg ? XrF_i : XrF_t;
        ushort_t* XhF = isImg ? XhF_i : XhF_t;
        ushort_t* AF  = isImg ? AF_i  : AF_t;
        int rbase = (isImg ? bx - 64 : bx) * 64;
        int statOff = isImg ? 4096 : 0;
        int d0 = by * 64;
        #pragma unroll
        for (int rep = 0; rep < 4; ++rep) {
            int rl = (t >> 4) + rep * 16;
            int c4 = (t & 15) * 4;
            *(float4*)&tile[rl][c4] = *(const float4*)(x + (size_t)(rbase + rl) * D_ + d0 + c4);
        }
        if (t < 64) { mu_s[t] = mu[statOff + rbase + t]; rs_s[t] = rstd[statOff + rbase + t]; }
        __syncthreads();
        int lane = t & 63;
        #pragma unroll
        for (int rep = 0; rep < 2; ++rep) {
            int idx = t + rep * 256;
            int nt = (idx >> 6) & 3, cl = (idx >> 8) & 1;
            int kl = cl * 32 + (lane >> 4) * 8;
            int nl = nt * 16 + (lane & 15);
            ushort_t orw[8], oh[8];
            #pragma unroll
            for (int j = 0; j < 8; ++j) {
                float v = tile[kl + j][nl];
                orw[j] = f2bf(v);
                oh[j]  = f2bf((v - mu_s[kl + j]) * rs_s[kl + j]);
            }
            size_t chunk = (size_t)((rbase >> 5) + cl);
            size_t o = ((chunk * 48 + (d0 >> 4) + nt) * 64 + lane) * 8;
            *reinterpret_cast<uint4*>(XrF + o) = *reinterpret_cast<uint4*>(orw);
            *reinterpret_cast<uint4*>(XhF + o) = *reinterpret_cast<uint4*>(oh);
        }
        #pragma unroll
        for (int rep = 0; rep < 2; ++rep) {
            int idx = t + rep * 256;
            int cl = (idx >> 6) & 1, tl = idx >> 7;
            int rl = tl * 16 + (lane & 15);
            int dl = cl * 32 + (lane >> 4) * 8;
            float m = mu_s[rl], rs = rs_s[rl];
            ushort_t o8[8];
            #pragma unroll
            for (int j = 0; j < 8; ++j)
                o8[j] = f2bf((tile[rl][dl + j] - m) * rs);
            size_t o = (((size_t)(rbase >> 4) + tl) * 24 + (d0 >> 5) + cl) * 512 + lane * 8;
            *reinterpret_cast<uint4*>(AF + o) = *reinterpret_cast<uint4*>(o8);
        }
        return;
    }
    // t-projection sgemm: t = LN(lat)@(g*W)+bias, split-K atomics
    {
        int f = bid - 1152;
        int bx = f % 4, by = (f / 4) % 2, z = f / 8;   // z in 0..11, nz0=6
        int cfg = (z >= 6) ? 1 : 0;
        int kz = cfg ? z - 6 : z;
        sgemm_body(smem, t,
                   lat, cfg ? i_tp_w : t_tp_w, cfg ? i_tn_g : t_tn_g,
                   cfg ? b_tp_i : b_tp_t, mu, rstd, 6144,
                   cfg ? t_i : t_t, kz, bx, by, D_, E_);
    }
}

// ===========================================================================
// stage3: c2-gemm (32) + sproj (192) + pack_M (8192) = 8416 blocks.
// dyn LDS 18432 B. Small blocks first so they overlap pack_M's long dispatch.
// ===========================================================================
__global__ __launch_bounds__(256) void stage3_kernel(
    const float* __restrict__ t_t, const float* __restrict__ t_i,
    const float* __restrict__ t_m1_w, const float* __restrict__ t_m1_b,
    const float* __restrict__ i_m1_w, const float* __restrict__ i_m1_b,
    float* __restrict__ c2_t, float* __restrict__ c2_i,
    const ushort_t* __restrict__ AF_t, const ushort_t* __restrict__ BF_t,
    const float* __restrict__ b_su_t, ushort_t* __restrict__ sF_t,
    const ushort_t* __restrict__ AF_i, const ushort_t* __restrict__ BF_i,
    const float* __restrict__ b_su_i, ushort_t* __restrict__ sF_i,
    ushort_t* __restrict__ MF_t, ushort_t* __restrict__ MF_i)
{
    extern __shared__ __align__(16) char smem[];
    int bid = blockIdx.x;
    int tid = threadIdx.x;
    if (bid < 32) {
        // c2 = t @ W2 + m1_b
        int bx = bid % 4, by = (bid / 4) % 2, z = bid / 8;  // z 0..3, nz0=2
        int cfg = (z >= 2) ? 1 : 0;
        int kz = cfg ? z - 2 : z;
        sgemm_body(smem, tid,
                   cfg ? t_i : t_t,
                   (cfg ? i_m1_w : t_m1_w) + (size_t)E_ * E_, nullptr,
                   cfg ? i_m1_b : t_m1_b, nullptr, nullptr, 0,
                   cfg ? c2_i : c2_t, kz, bx, by, E_, E_);
        return;
    }
    if (bid < 224) {
        // sproj: s = xhat@Wf + bias -> sF A-frags
        int bx = bid - 32;
        int isImg = bx >= 128;
        const ushort_t* AF = isImg ? AF_i : AF_t;
        const ushort_t* BF = isImg ? BF_i : BF_t;
        const float* bias = isImg ? b_su_i : b_su_t;
        ushort_t* sF = isImg ? sF_i : sF_t;
        int tile0 = (isImg ? bx - 128 : bx) * 2;
        ushort_t* lsbase = (ushort_t*)smem;   // [4*32][72]
        int w = tid >> 6, lane = tid & 63;
        int quad = lane >> 4, n16 = lane & 15;
        f32x4 acc[2][4];
        #pragma unroll
        for (int mt = 0; mt < 2; ++mt)
            #pragma unroll
            for (int nt = 0; nt < 4; ++nt)
                acc[mt][nt] = (f32x4){0.f, 0.f, 0.f, 0.f};
        for (int c = 0; c < 24; ++c) {
            bf16x8 af[2], bf[4];
            #pragma unroll
            for (int mt = 0; mt < 2; ++mt)
                af[mt] = *reinterpret_cast<const bf16x8*>(AF + ((size_t)(tile0 + mt) * 24 + c) * 512 + lane * 8);
            #pragma unroll
            for (int nt = 0; nt < 4; ++nt)
                bf[nt] = *reinterpret_cast<const bf16x8*>(BF + ((size_t)c * 16 + w * 4 + nt) * 512 + lane * 8);
            #pragma unroll
            for (int mt = 0; mt < 2; ++mt)
                #pragma unroll
                for (int nt = 0; nt < 4; ++nt)
                    acc[mt][nt] = __builtin_amdgcn_mfma_f32_16x16x32_bf16(af[mt], bf[nt], acc[mt][nt], 0, 0, 0);
        }
        #pragma unroll
        for (int mt = 0; mt < 2; ++mt)
            #pragma unroll
            for (int nt = 0; nt < 4; ++nt) {
                float bv = bias[w * 64 + nt * 16 + n16];
                #pragma unroll
                for (int r = 0; r < 4; ++r)
                    lsbase[(w * 32 + mt * 16 + quad * 4 + r) * 72 + nt * 16 + n16] = f2bf(acc[mt][nt][r] + bv);
            }
        __syncthreads();
        #pragma unroll
        for (int mt = 0; mt < 2; ++mt)
            #pragma unroll
            for (int h = 0; h < 2; ++h) {
                uint4 v = *reinterpret_cast<const uint4*>(&lsbase[(w * 32 + mt * 16 + n16) * 72 + h * 32 + quad * 8]);
                *reinterpret_cast<uint4*>(sF + ((size_t)(tile0 + mt) * 8 + 2 * w + h) * 512 + lane * 8) = v;
            }
        return;
    }
    // pack_M: M_k = t[k,e]*W3[e,j] + W1[e,j]
    {
        const int HALF = B_ * K_ * 16 * 8 * 64;   // 1048576
        int gidx = (bid - 224) * 256 + tid;
        int isImg = gidx >= HALF;
        int idx = isImg ? gidx - HALF : gidx;
        const float* tP = isImg ? t_i : t_t;
        const float* W3 = (isImg ? i_m1_w : t_m1_w) + 2 * (size_t)E_ * E_;
        const float* W1 = isImg ? i_m1_w : t_m1_w;
        ushort_t* MF = isImg ? MF_i : MF_t;
        int lane = idx & 63;
        int kc = (idx >> 6) & 7;
        int nt = (idx >> 9) & 15;
        int bk = idx >> 13;
        int n = nt * 16 + (lane & 15);
        int e0 = kc * 32 + (lane >> 4) * 8;
        ushort_t out[8];
        #pragma unroll
        for (int j = 0; j < 8; ++j) {
            int e = e0 + j;
            float v = tP[(size_t)bk * E_ + e] * W3[(size_t)e * E_ + n] + W1[(size_t)e * E_ + n];
            out[j] = f2bf(v);
        }
        *reinterpret_cast<uint4*>(MF + (size_t)idx * 8) = *reinterpret_cast<uint4*>(out);
    }
}

// ===========================================================================
// Cross + edge via MFMA. grid (K=64, 48, B), k fastest. Writes Etmp[b][k][s].
// launch_bounds(256,4): ~128 total regs; (256,6) spilled in R6 — do not raise.
// Accumulators MUST init to zero (R11: c2-in-init caused 62 MB spill traffic).
// Epilogue: z = acc + c2; gelu = z*sigmoid(1.702z) via raw v_exp_f32.
// ===========================================================================
__global__ __launch_bounds__(256, 4) void cross_mfma_kernel(
    const ushort_t* __restrict__ sF_t, const ushort_t* __restrict__ MF_t,
    const float* __restrict__ c2_t, const float* __restrict__ m2w_t,
    const float* __restrict__ m2b_t, const float* __restrict__ mask_t,
    float* __restrict__ Et,
    const ushort_t* __restrict__ sF_i, const ushort_t* __restrict__ MF_i,
    const float* __restrict__ c2_i, const float* __restrict__ m2w_i,
    const float* __restrict__ m2b_i, const float* __restrict__ mask_i,
    float* __restrict__ Ei)
{
    int k = blockIdx.x;
    int by = blockIdx.y;
    int isImg = by >= 32;
    int S = isImg ? SI_ : ST_;
    const ushort_t* sF = isImg ? sF_i : sF_t;
    const ushort_t* MF = isImg ? MF_i : MF_t;
    const float* c2P = isImg ? c2_i : c2_t;
    const float* m2w = isImg ? m2w_i : m2w_t;
    const float* m2b = isImg ? m2b_i : m2b_t;
    const float* mask = isImg ? mask_i : mask_t;
    float* Etmp = isImg ? Ei : Et;
    int s0 = (isImg ? by - 32 : by) * 64;
    int b = blockIdx.z;
    int tid = threadIdx.x;
    int w = tid >> 6, lane = tid & 63;
    int quad = lane >> 4, n16 = lane & 15;

    const ushort_t* aBase = sF + (size_t)(b * (S / 16) + (s0 >> 4)) * 4096;
    const ushort_t* bBase = MF + ((size_t)(b * K_ + k) * 16 + w * 4) * 4096;

    f32x4 acc[4][4];
    #pragma unroll
    for (int mt = 0; mt < 4; ++mt)
        #pragma unroll
        for (int nt = 0; nt < 4; ++nt)
            acc[mt][nt] = (f32x4){0.f, 0.f, 0.f, 0.f};

    #pragma unroll
    for (int kc = 0; kc < 8; ++kc) {
        bf16x8 bfr[4], af[4];
        #pragma unroll
        for (int nt = 0; nt < 4; ++nt)
            bfr[nt] = *reinterpret_cast<const bf16x8*>(bBase + (size_t)nt * 4096 + kc * 512 + lane * 8);
        #pragma unroll
        for (int mt = 0; mt < 4; ++mt)
            af[mt] = *reinterpret_cast<const bf16x8*>(aBase + (size_t)mt * 4096 + kc * 512 + lane * 8);
        #pragma unroll
        for (int mt = 0; mt < 4; ++mt)
            #pragma unroll
            for (int nt = 0; nt < 4; ++nt)
                acc[mt][nt] = __builtin_amdgcn_mfma_f32_16x16x32_bf16(af[mt], bfr[nt], acc[mt][nt], 0, 0, 0);
    }

    const float* c2v = c2P + (size_t)(b * K_ + k) * E_;
    float c2r[4], m2r[4];
    #pragma unroll
    for (int nt = 0; nt < 4; ++nt) {
        int col = w * 64 + nt * 16 + n16;
        c2r[nt] = c2v[col];
        m2r[nt] = m2w[col];
    }
    __shared__ float pPart[4][64];
    #pragma unroll
    for (int mt = 0; mt < 4; ++mt) {
        #pragma unroll
        for (int r = 0; r < 4; ++r) {
            float p = 0.f;
            #pragma unroll
            for (int nt = 0; nt < 4; ++nt) {
                float z = acc[mt][nt][r] + c2r[nt];
                // sigmoid-gelu: m2*z*sigmoid(1.702z); -1.702*log2(e) = -2.4554670
                float u = z * -2.4554670f;
                float t;
                asm("v_exp_f32 %0, %1" : "=v"(t) : "v"(u));
                float sg = __builtin_amdgcn_rcpf(1.0f + t);
                p = fmaf(m2r[nt] * z, sg, p);
            }
            p += __shfl_xor(p, 1, 64);
            p += __shfl_xor(p, 2, 64);
            p += __shfl_xor(p, 4, 64);
            p += __shfl_xor(p, 8, 64);
            if (n16 == 0) pPart[w][mt * 16 + quad * 4 + r] = p;
        }
    }
    __syncthreads();
    if (tid < 64) {
        float e = pPart[0][tid] + pPart[1][tid] + pPart[2][tid] + pPart[3][tid] + m2b[0];
        e = e / (1.0f + fabsf(e));
        int srow = s0 + tid;
        e *= mask[(size_t)b * S + srow];
        Etmp[(size_t)(b * K_ + k) * S + srow] = e;   // coalesced 256 B/block
    }
}

// ===========================================================================
// packE2: read Etmp[b][k][s] coalesced; write t2l/i2l, EF A-frags, rowsum.
// ===========================================================================
__global__ __launch_bounds__(256) void packE2_kernel(
    const float* __restrict__ Et, const float* __restrict__ Ei,
    float* __restrict__ t2l, float* __restrict__ i2l,
    ushort_t* __restrict__ EF_t, ushort_t* __restrict__ EF_i,
    float* __restrict__ rs_t, float* __restrict__ rs_i)
{
    __shared__ float tile[64][33];   // [k][s]
    int g = blockIdx.x;
    int isImg = g >= 128;
    const float* Esrc = isImg ? Ei : Et;
    float* dst = isImg ? i2l : t2l;
    ushort_t* EF = isImg ? EF_i : EF_t;
    float* rsum = isImg ? rs_i : rs_t;
    int chunk = isImg ? g - 128 : g;
    int S = isImg ? SI_ : ST_;
    int b = (chunk * 32) / S;
    int s0 = (chunk * 32) % S;
    int t = threadIdx.x;
    {
        int k = t >> 2, si = (t & 3) * 8;
        const float* p = Esrc + (size_t)(b * K_ + k) * S + s0 + si;
        *(float4*)&tile[k][si] = *(const float4*)p;
        *(float4*)&tile[k][si + 4] = *(const float4*)(p + 4);
    }
    __syncthreads();
    {
        int s = t >> 3, k0 = (t & 7) * 8;
        float o[8];
        #pragma unroll
        for (int j = 0; j < 8; ++j) o[j] = tile[k0 + j][s];
        float* p = dst + ((size_t)b * S + s0 + s) * K_ + k0;
        *(float4*)p = *(float4*)&o[0];
        *(float4*)(p + 4) = *(float4*)&o[4];
    }
    {
        int mt = t >> 6, lane = t & 63;
        int k = mt * 16 + (lane & 15);
        int sl0 = (lane >> 4) * 8;
        ushort_t o8[8];
        #pragma unroll
        for (int j = 0; j < 8; ++j)
            o8[j] = f2bf(tile[k][sl0 + j]);
        *reinterpret_cast<uint4*>(EF + (((size_t)chunk * 4 + mt) * 64 + lane) * 8) = *reinterpret_cast<uint4*>(o8);
    }
    if (t < 64) {
        float s = 0.f;
        #pragma unroll
        for (int j = 0; j < 32; ++j) s += tile[t][j];
        atomicAdd(&rsum[b * K_ + t], s);
    }
}

// ===========================================================================
// einsum via MFMA, atomic accumulate directly into Gt/Gi/Racc (no partials).
// grid (6, 16, 4): bz<2 text (b=bz), else image. nt=2/wave.
// ===========================================================================
__global__ __launch_bounds__(256, 4) void einsum_mfma_kernel(
    const ushort_t* __restrict__ EF_t, const ushort_t* __restrict__ XhF_t,
    const ushort_t* __restrict__ XrF_t,
    const ushort_t* __restrict__ EF_i, const ushort_t* __restrict__ XhF_i,
    const ushort_t* __restrict__ XrF_i,
    float* __restrict__ Gt, float* __restrict__ Gi, float* __restrict__ Racc)
{
    int bz = blockIdx.z;
    int isImg = bz >= 2;
    int b = isImg ? bz - 2 : bz;
    int S = isImg ? SI_ : ST_;
    const ushort_t* EF = isImg ? EF_i : EF_t;
    const ushort_t* XhF = isImg ? XhF_i : XhF_t;
    const ushort_t* XrF = isImg ? XrF_i : XrF_t;
    float* G = isImg ? Gi : Gt;
    int chunksPerBlock = isImg ? 2 : 4;

    int w = threadIdx.x >> 6, lane = threadIdx.x & 63;
    int quad = lane >> 4, n16 = lane & 15;
    int y = blockIdx.y;
    int nt0 = blockIdx.x * 8 + w * 2;
    size_t cb = (size_t)(b * S) / 32 + (size_t)y * chunksPerBlock;

    f32x4 aG[4][2], aR[4][2];
    #pragma unroll
    for (int mt = 0; mt < 4; ++mt)
        #pragma unroll
        for (int nt = 0; nt < 2; ++nt) {
            aG[mt][nt] = (f32x4){0.f, 0.f, 0.f, 0.f};
            aR[mt][nt] = (f32x4){0.f, 0.f, 0.f, 0.f};
        }

    for (int cc = 0; cc < chunksPerBlock; ++cc) {
        size_t c = cb + cc;
        bf16x8 af[4], bh[2], bx[2];
        #pragma unroll
        for (int mt = 0; mt < 4; ++mt)
            af[mt] = *reinterpret_cast<const bf16x8*>(EF + ((c * 4 + mt) * 64 + lane) * 8);
        #pragma unroll
        for (int nt = 0; nt < 2; ++nt) {
            bh[nt] = *reinterpret_cast<const bf16x8*>(XhF + ((c * 48 + nt0 + nt) * 64 + lane) * 8);
            bx[nt] = *reinterpret_cast<const bf16x8*>(XrF + ((c * 48 + nt0 + nt) * 64 + lane) * 8);
        }
        #pragma unroll
        for (int mt = 0; mt < 4; ++mt)
            #pragma unroll
            for (int nt = 0; nt < 2; ++nt) {
                aG[mt][nt] = __builtin_amdgcn_mfma_f32_16x16x32_bf16(af[mt], bh[nt], aG[mt][nt], 0, 0, 0);
                aR[mt][nt] = __builtin_amdgcn_mfma_f32_16x16x32_bf16(af[mt], bx[nt], aR[mt][nt], 0, 0, 0);
            }
    }
    #pragma unroll
    for (int mt = 0; mt < 4; ++mt)
        #pragma unroll
        for (int nt = 0; nt < 2; ++nt) {
            int d = (nt0 + nt) * 16 + n16;
            #pragma unroll
            for (int r = 0; r < 4; ++r) {
                int krow = mt * 16 + quad * 4 + r;
                size_t o = ((size_t)(b * K_ + krow)) * D_ + d;
                atomicAdd(&G[o], aG[mt][nt][r]);
                atomicAdd(&Racc[o], aR[mt][nt][r]);
            }
        }
}

// ---------------------------------------------------------------------------
// sgemm3: state_tmp = Gt@(g*tsp_w) + Gi@(g*isp_w), split-K atomics.
// grid flat 288, dyn LDS 8256 B
// ---------------------------------------------------------------------------
__global__ __launch_bounds__(256) void sgemm3_kernel(
    const float* __restrict__ Gt, const float* __restrict__ tsp_w, const float* __restrict__ tsn_g,
    const float* __restrict__ Gi, const float* __restrict__ isp_w, const float* __restrict__ isn_g,
    float* __restrict__ state_tmp)
{
    extern __shared__ __align__(16) char smem[];
    int f = blockIdx.x;
    int bx = f % 12, by = (f / 12) % 2, z = f / 24;  // z 0..11, nz0=6
    int cfg = (z >= 6) ? 1 : 0;
    int kz = cfg ? z - 6 : z;
    sgemm_body(smem, threadIdx.x,
               cfg ? Gi : Gt, cfg ? isp_w : tsp_w, cfg ? isn_g : tsn_g,
               nullptr, nullptr, nullptr, 0, state_tmp, kz, bx, by, D_, D_);
}

// ---------------------------------------------------------------------------
__global__ __launch_bounds__(256) void final_ln_kernel(
    const float* __restrict__ stateTmp, const float* __restrict__ Racc,
    const float* __restrict__ rs_t, const float* __restrict__ rs_i,
    const float* __restrict__ b_tspf, const float* __restrict__ b_ispf,
    const float* __restrict__ state_init, const float* __restrict__ value_init,
    const float* __restrict__ stn_g, const float* __restrict__ stn_b,
    const float* __restrict__ vn_g, const float* __restrict__ vn_b,
    float* __restrict__ outState, float* __restrict__ outValue)
{
    __shared__ float pre[D_];
    __shared__ float red[256];
    int idx = blockIdx.x;
    int row = idx & 127;
    int isVal = idx >> 7;
    int tid = threadIdx.x;
    if (!isVal) {
        float rt = rs_t[row], ri = rs_i[row];
        for (int d = tid; d < D_; d += 256)
            pre[d] = stateTmp[(size_t)row * D_ + d] + rt * b_tspf[d] + ri * b_ispf[d]
                   + state_init[(size_t)row * D_ + d];
    } else {
        for (int d = tid; d < D_; d += 256)
            pre[d] = Racc[(size_t)row * D_ + d] + value_init[(size_t)row * D_ + d];
    }
    __syncthreads();
    float s = 0.f;
    for (int d = tid; d < D_; d += 256) s += pre[d];
    red[tid] = s; __syncthreads();
    for (int off = 128; off > 0; off >>= 1) { if (tid < off) red[tid] += red[tid + off]; __syncthreads(); }
    float mu = red[0] / (float)D_;
    __syncthreads();
    float v = 0.f;
    for (int d = tid; d < D_; d += 256) { float t = pre[d] - mu; v += t * t; }
    red[tid] = v; __syncthreads();
    for (int off = 128; off > 0; off >>= 1) { if (tid < off) red[tid] += red[tid + off]; __syncthreads(); }
    float rstd = rsqrtf(red[0] / (float)D_ + EPS_LN);
    const float* g  = isVal ? vn_g : stn_g;
    const float* bb = isVal ? vn_b : stn_b;
    float* o = (isVal ? outValue : outState) + (size_t)row * D_;
    for (int d = tid; d < D_; d += 256) o[d] = (pre[d] - mu) * rstd * g[d] + bb[d];
}

// ---------------------------------------------------------------------------
extern "C" void kernel_launch(void* const* d_in, const int* in_sizes, int n_in,
                              void* d_out, int out_size, void* d_ws, size_t ws_size,
                              hipStream_t stream) {
    const float* text_values  = (const float*)d_in[0];
    const float* image_values = (const float*)d_in[1];
    const float* lstate_init  = (const float*)d_in[2];
    const float* lvalue_init  = (const float*)d_in[3];
    const float* text_mask    = (const float*)d_in[4];
    const float* image_mask   = (const float*)d_in[5];
    const float* t_sn_g = (const float*)d_in[6];
    const float* t_sn_b = (const float*)d_in[7];
    const float* t_tn_g = (const float*)d_in[8];
    const float* t_tn_b = (const float*)d_in[9];
    const float* t_su_w = (const float*)d_in[10];
    const float* t_su_b = (const float*)d_in[11];
    const float* t_tp_w = (const float*)d_in[12];
    const float* t_tp_b = (const float*)d_in[13];
    const float* t_m1_w = (const float*)d_in[14];
    const float* t_m1_b = (const float*)d_in[15];
    const float* t_m2_w = (const float*)d_in[16];
    const float* t_m2_b = (const float*)d_in[17];
    const float* i_sn_g = (const float*)d_in[18];
    const float* i_sn_b = (const float*)d_in[19];
    const float* i_tn_g = (const float*)d_in[20];
    const float* i_tn_b = (const float*)d_in[21];
    const float* i_su_w = (const float*)d_in[22];
    const float* i_su_b = (const float*)d_in[23];
    const float* i_tp_w = (const float*)d_in[24];
    const float* i_tp_b = (const float*)d_in[25];
    const float* i_m1_w = (const float*)d_in[26];
    const float* i_m1_b = (const float*)d_in[27];
    const float* i_m2_w = (const float*)d_in[28];
    const float* i_m2_b = (const float*)d_in[29];
    const float* tsn_g = (const float*)d_in[30];
    const float* tsn_b = (const float*)d_in[31];
    const float* isn_g = (const float*)d_in[32];
    const float* isn_b = (const float*)d_in[33];
    const float* stn_g = (const float*)d_in[34];
    const float* stn_b = (const float*)d_in[35];
    const float* vn_g  = (const float*)d_in[36];
    const float* vn_b  = (const float*)d_in[37];
    const float* tsp_w = (const float*)d_in[38];
    const float* tsp_b = (const float*)d_in[39];
    const float* isp_w = (const float*)d_in[40];
    const float* isp_b = (const float*)d_in[41];

    float* ws = (float*)d_ws;
    size_t o = 0;
    float* stats_mu = ws + o; o += 6272;
    float* stats_rs = ws + o; o += 6272;
    // --- zeroed block (contiguous) ---
    float* zeroBase = ws + o;
    float* b_su_t = ws + o; o += E_;
    float* b_su_i = ws + o; o += E_;
    float* b_tp_t = ws + o; o += E_;
    float* b_tp_i = ws + o; o += E_;
    float* b_tspf = ws + o; o += D_;
    float* b_ispf = ws + o; o += D_;
    float* t_t  = ws + o; o += (size_t)B_ * K_ * E_;
    float* t_i  = ws + o; o += (size_t)B_ * K_ * E_;
    float* c2_t = ws + o; o += (size_t)B_ * K_ * E_;
    float* c2_i = ws + o; o += (size_t)B_ * K_ * E_;
    float* state_tmp = ws + o; o += (size_t)B_ * K_ * D_;
    float* rs_t = ws + o; o += 128;
    float* rs_i = ws + o; o += 128;
    const int BKD = B_ * K_ * D_;
    float* Gt   = ws + o; o += BKD;
    float* Gi   = ws + o; o += BKD;
    float* Racc = ws + o; o += BKD;
    size_t zeroFloats = (size_t)(4 * E_ + 2 * D_ + 4 * B_ * K_ * E_ + B_ * K_ * D_ + 256 + 3 * BKD);
    // --- end zeroed block ---
    float* Etmp_t = ws + o; o += (size_t)B_ * K_ * ST_;
    float* Etmp_i = ws + o; o += (size_t)B_ * K_ * SI_;
    ushort_t* AF_t = (ushort_t*)(ws + o); o += (size_t)B_ * ST_ * D_ / 2;
    ushort_t* AF_i = (ushort_t*)(ws + o); o += (size_t)B_ * SI_ * D_ / 2;
    ushort_t* WsuF_t = (ushort_t*)(ws + o); o += (size_t)D_ * E_ / 2;
    ushort_t* WsuF_i = (ushort_t*)(ws + o); o += (size_t)D_ * E_ / 2;
    ushort_t* sF_t = (ushort_t*)(ws + o); o += (size_t)B_ * ST_ * E_ / 2;
    ushort_t* sF_i = (ushort_t*)(ws + o); o += (size_t)B_ * SI_ * E_ / 2;
    ushort_t* MF_t = (ushort_t*)(ws + o); o += (size_t)B_ * K_ * E_ * E_ / 2;
    ushort_t* MF_i = (ushort_t*)(ws + o); o += (size_t)B_ * K_ * E_ * E_ / 2;
    ushort_t* XhF_t = (ushort_t*)(ws + o); o += (size_t)B_ * ST_ * D_ / 2;
    ushort_t* XhF_i = (ushort_t*)(ws + o); o += (size_t)B_ * SI_ * D_ / 2;
    ushort_t* XrF_t = (ushort_t*)(ws + o); o += (size_t)B_ * ST_ * D_ / 2;
    ushort_t* XrF_i = (ushort_t*)(ws + o); o += (size_t)B_ * SI_ * D_ / 2;
    ushort_t* EF_t  = (ushort_t*)(ws + o); o += (size_t)B_ * ST_ * K_ / 2;
    ushort_t* EF_i  = (ushort_t*)(ws + o); o += (size_t)B_ * SI_ * K_ / 2;

    float* outState = (float*)d_out;
    float* outValue = (float*)d_out + (size_t)B_ * K_ * D_;
    float* t2l = (float*)d_out + 2 * (size_t)B_ * K_ * D_;
    float* i2l = t2l + (size_t)B_ * ST_ * K_;

    hipMemsetAsync(zeroBase, 0, zeroFloats * sizeof(float), stream);

    prelude_kernel<<<2624, 256, 1024, stream>>>(
        text_values, image_values, lvalue_init, stats_mu, stats_rs,
        t_sn_b, t_su_w, t_su_b, b_su_t,
        i_sn_b, i_su_w, i_su_b, b_su_i,
        t_tn_b, t_tp_w, t_tp_b, b_tp_t,
        i_tn_b, i_tp_w, i_tp_b, b_tp_i,
        tsn_b, tsp_w, tsp_b, b_tspf,
        isn_b, isp_w, isp_b, b_ispf,
        t_su_w, t_sn_g, WsuF_t,
        i_su_w, i_sn_g, WsuF_i);

    stage2_kernel<<<1248, 256, 17152, stream>>>(
        text_values, image_values, stats_mu, stats_rs,
        XrF_t, XhF_t, AF_t, XrF_i, XhF_i, AF_i,
        lvalue_init,
        t_tp_w, t_tn_g, b_tp_t, t_t,
        i_tp_w, i_tn_g, b_tp_i, t_i);

    stage3_kernel<<<8416, 256, 18432, stream>>>(
        t_t, t_i, t_m1_w, t_m1_b, i_m1_w, i_m1_b, c2_t, c2_i,
        AF_t, WsuF_t, b_su_t, sF_t,
        AF_i, WsuF_i, b_su_i, sF_i,
        MF_t, MF_i);

    cross_mfma_kernel<<<dim3(K_, 48, B_), 256, 0, stream>>>(
        sF_t, MF_t, c2_t, t_m2_w, t_m2_b, text_mask, Etmp_t,
        sF_i, MF_i, c2_i, i_m2_w, i_m2_b, image_mask, Etmp_i);

    packE2_kernel<<<192, 256, 0, stream>>>(
        Etmp_t, Etmp_i, t2l, i2l, EF_t, EF_i, rs_t, rs_i);

    einsum_mfma_kernel<<<dim3(6, 16, 4), 256, 0, stream>>>(
        EF_t, XhF_t, XrF_t,
        EF_i, XhF_i, XrF_i,
        Gt, Gi, Racc);

    sgemm3_kernel<<<288, 256, 8256, stream>>>(
        Gt, tsp_w, tsn_g, Gi, isp_w, isn_g, state_tmp);

    final_ln_kernel<<<2 * B_ * K_, 256, 0, stream>>>(
        state_tmp, Racc, rs_t, rs_i, b_tspf, b_ispf,
        lstate_init, lvalue_init, stn_g, stn_b, vn_g, vn_b, outState, outValue);
}

// Round 14
// 330.796 us; speedup vs baseline: 1.0016x; 1.0016x over previous
//
#include <hip/hip_runtime.h>
#include <math.h>

#define EPS_LN 1e-5f

#define B_  2
#define ST_ 2048
#define SI_ 1024
#define K_  64
#define D_  768
#define E_  256

typedef __bf16 bf16x8 __attribute__((ext_vector_type(8)));
typedef float  f32x4  __attribute__((ext_vector_type(4)));
typedef unsigned short ushort_t;

__device__ inline ushort_t f2bf(float x) {
    unsigned int u = __float_as_uint(x);
    unsigned int r = (u + 0x7FFFu + ((u >> 16) & 1u)) >> 16;
    return (ushort_t)r;
}

// ===========================================================================
// Device bodies for fused kernels
// ===========================================================================

__device__ void ln_stats_body(int bid, int tid,
    const float* __restrict__ xt, const float* __restrict__ xi,
    const float* __restrict__ xl, float* __restrict__ mu, float* __restrict__ rstd)
{
    int w = tid >> 6, lane = tid & 63;
    int row = bid * 4 + w;
    const float* src;
    if (row < 4096) src = xt + (size_t)row * D_;
    else if (row < 6144) src = xi + (size_t)(row - 4096) * D_;
    else src = xl + (size_t)(row - 6144) * D_;
    float s = 0.f, q = 0.f;
    #pragma unroll
    for (int rep = 0; rep < 3; ++rep) {
        float4 v = *(const float4*)(src + lane * 4 + rep * 256);
        s += v.x + v.y + v.z + v.w;
        q += v.x * v.x + v.y * v.y + v.z * v.z + v.w * v.w;
    }
    #pragma unroll
    for (int off = 32; off > 0; off >>= 1) {
        s += __shfl_xor(s, off, 64);
        q += __shfl_xor(q, off, 64);
    }
    if (lane == 0) {
        float m = s / (float)D_;
        float var = q / (float)D_ - m * m;
        mu[row] = m;
        rstd[row] = rsqrtf(var + EPS_LN);
    }
}

__device__ void sgemm_body(char* smem, int tid,
    const float* __restrict__ A, const float* __restrict__ Bm,
    const float* __restrict__ rowScale, const float* __restrict__ bias,
    const float* __restrict__ muA, const float* __restrict__ sdA, int so,
    float* __restrict__ C, int kz, int bx, int by, int Kd, int N)
{
    float (*As)[65] = (float(*)[65])smem;
    float (*Bs)[64] = (float(*)[64])(smem + 16 * 65 * 4);
    int tx = tid & 15, ty = tid >> 4;
    int row0 = by * 64;
    int col0 = bx * 64;
    float acc[4][4] = {};
    int kbase = kz * 128;
    for (int k0 = kbase; k0 < kbase + 128; k0 += 16) {
        {
            int e = tid * 4;
            int r = e >> 4, kk = e & 15;
            float4 av = *(const float4*)(A + (size_t)(row0 + r) * Kd + k0 + kk);
            if (muA) {
                float m = muA[so + row0 + r], sd = sdA[so + row0 + r];
                av.x = (av.x - m) * sd; av.y = (av.y - m) * sd;
                av.z = (av.z - m) * sd; av.w = (av.w - m) * sd;
            }
            As[kk + 0][r] = av.x; As[kk + 1][r] = av.y; As[kk + 2][r] = av.z; As[kk + 3][r] = av.w;
        }
        {
            int e = tid * 4;
            int kk = e >> 6, c = e & 63;
            float4 bv = *(const float4*)(Bm + (size_t)(k0 + kk) * N + col0 + c);
            if (rowScale) {
                float sc = rowScale[k0 + kk];
                bv.x *= sc; bv.y *= sc; bv.z *= sc; bv.w *= sc;
            }
            *(float4*)&Bs[kk][c] = bv;
        }
        __syncthreads();
        #pragma unroll
        for (int kk = 0; kk < 16; ++kk) {
            float a[4], b[4];
            #pragma unroll
            for (int i = 0; i < 4; ++i) a[i] = As[kk][ty + 16 * i];
            #pragma unroll
            for (int j = 0; j < 4; ++j) b[j] = Bs[kk][tx + 16 * j];
            #pragma unroll
            for (int i = 0; i < 4; ++i)
                #pragma unroll
                for (int j = 0; j < 4; ++j)
                    acc[i][j] += a[i] * b[j];
        }
        __syncthreads();
    }
    #pragma unroll
    for (int i = 0; i < 4; ++i) {
        int r = row0 + ty + 16 * i;
        #pragma unroll
        for (int j = 0; j < 4; ++j) {
            int c = col0 + tx + 16 * j;
            float v = acc[i][j];
            if (kz == 0 && bias) v += bias[c];
            atomicAdd(&C[(size_t)r * N + c], v);
        }
    }
}

// ===========================================================================
// prelude: ln_stats (1568) + fold_all (864) + packB2 (192) = 2624 blocks
// dyn LDS: 1024 B
// ===========================================================================
__global__ __launch_bounds__(256) void prelude_kernel(
    const float* __restrict__ xt, const float* __restrict__ xi,
    const float* __restrict__ xl, float* __restrict__ mu, float* __restrict__ rstd,
    const float* b0, const float* W0, const float* w0, float* f0,
    const float* b1, const float* W1, const float* w1, float* f1,
    const float* b2, const float* W2, const float* w2, float* f2,
    const float* b3, const float* W3, const float* w3, float* f3,
    const float* b4, const float* W4, const float* w4, float* f4,
    const float* b5, const float* W5, const float* w5, float* f5,
    const float* __restrict__ Wsu_t, const float* __restrict__ g_t, ushort_t* __restrict__ WF_t,
    const float* __restrict__ Wsu_i, const float* __restrict__ g_i, ushort_t* __restrict__ WF_i)
{
    extern __shared__ __align__(16) char smem[];
    int bid = blockIdx.x;
    int tid = threadIdx.x;
    if (bid < 1568) {
        ln_stats_body(bid, tid, xt, xi, xl, mu, rstd);
        return;
    }
    if (bid < 2432) {
        // fold_all
        int f = bid - 1568;
        int ebx = f % 12, dby = (f / 12) % 12, cfg = f / 144;
        const float* blns[6] = {b0, b1, b2, b3, b4, b5};
        const float* Ws[6]   = {W0, W1, W2, W3, W4, W5};
        const float* wbs[6]  = {w0, w1, w2, w3, w4, w5};
        float* bfs[6]        = {f0, f1, f2, f3, f4, f5};
        int E = (cfg >= 4) ? 768 : 256;
        if (ebx * 64 >= E) return;
        const float* bln = blns[cfg];
        const float* W = Ws[cfg];
        float (*red)[64] = (float(*)[64])smem;
        int c = tid & 63, part = tid >> 6;
        int e = ebx * 64 + c;
        int d0 = dby * 64;
        float s = 0.f;
        #pragma unroll
        for (int i = 0; i < 16; ++i) {
            int d = d0 + part * 16 + i;
            s += bln[d] * W[(size_t)d * E + e];
        }
        red[part][c] = s; __syncthreads();
        if (part == 0) {
            float v = red[0][c] + red[1][c] + red[2][c] + red[3][c];
            if (dby == 0 && wbs[cfg]) v += wbs[cfg][e];
            atomicAdd(&bfs[cfg][e], v);
        }
        return;
    }
    // packB2
    {
        const int HALF = (D_ >> 5) * (E_ >> 4) * 64;  // 24576
        int gidx = (bid - 2432) * 256 + tid;
        int isImg = gidx >= HALF;
        int idx = isImg ? gidx - HALF : gidx;
        const float* W = isImg ? Wsu_i : Wsu_t;
        const float* g = isImg ? g_i : g_t;
        ushort_t* out = isImg ? WF_i : WF_t;
        int lane = idx & 63;
        int ntile = (idx >> 6) & 15;
        int c = idx >> 10;
        int n = ntile * 16 + (lane & 15);
        int k0 = c * 32 + (lane >> 4) * 8;
        ushort_t o[8];
        #pragma unroll
        for (int j = 0; j < 8; ++j) {
            int k = k0 + j;
            o[j] = f2bf(W[(size_t)k * E_ + n] * g[k]);
        }
        *reinterpret_cast<uint4*>(out + (size_t)idx * 8) = *reinterpret_cast<uint4*>(o);
    }
}

// ===========================================================================
// stage2: tpack (1152) + t-proj sgemm (96) = 1248 blocks. dyn LDS 17152 B
// ===========================================================================
__global__ __launch_bounds__(256) void stage2_kernel(
    const float* __restrict__ xt, const float* __restrict__ xi,
    const float* __restrict__ mu, const float* __restrict__ rstd,
    ushort_t* __restrict__ XrF_t, ushort_t* __restrict__ XhF_t, ushort_t* __restrict__ AF_t,
    ushort_t* __restrict__ XrF_i, ushort_t* __restrict__ XhF_i, ushort_t* __restrict__ AF_i,
    const float* __restrict__ lat,
    const float* __restrict__ t_tp_w, const float* __restrict__ t_tn_g,
    const float* __restrict__ b_tp_t, float* __restrict__ t_t,
    const float* __restrict__ i_tp_w, const float* __restrict__ i_tn_g,
    const float* __restrict__ b_tp_i, float* __restrict__ t_i)
{
    extern __shared__ __align__(16) char smem[];
    int bid = blockIdx.x;
    int t = threadIdx.x;
    if (bid < 1152) {
        // tpack
        int bx = bid % 96, by = bid / 96;
        float (*tile)[65] = (float(*)[65])smem;
        float* mu_s = (float*)(smem + 64 * 65 * 4);
        float* rs_s = mu_s + 64;
        int isImg = bx >= 64;
        const float* x = isImg ? xi : xt;
        ushort_t* XrF = isImg ? XrF_i : XrF_t;
        ushort_t* XhF = isImg ? XhF_i : XhF_t;
        ushort_t* AF  = isImg ? AF_i  : AF_t;
        int rbase = (isImg ? bx - 64 : bx) * 64;
        int statOff = isImg ? 4096 : 0;
        int d0 = by * 64;
        #pragma unroll
        for (int rep = 0; rep < 4; ++rep) {
            int rl = (t >> 4) + rep * 16;
            int c4 = (t & 15) * 4;
            *(float4*)&tile[rl][c4] = *(const float4*)(x + (size_t)(rbase + rl) * D_ + d0 + c4);
        }
        if (t < 64) { mu_s[t] = mu[statOff + rbase + t]; rs_s[t] = rstd[statOff + rbase + t]; }
        __syncthreads();
        int lane = t & 63;
        #pragma unroll
        for (int rep = 0; rep < 2; ++rep) {
            int idx = t + rep * 256;
            int nt = (idx >> 6) & 3, cl = (idx >> 8) & 1;
            int kl = cl * 32 + (lane >> 4) * 8;
            int nl = nt * 16 + (lane & 15);
            ushort_t orw[8], oh[8];
            #pragma unroll
            for (int j = 0; j < 8; ++j) {
                float v = tile[kl + j][nl];
                orw[j] = f2bf(v);
                oh[j]  = f2bf((v - mu_s[kl + j]) * rs_s[kl + j]);
            }
            size_t chunk = (size_t)((rbase >> 5) + cl);
            size_t o = ((chunk * 48 + (d0 >> 4) + nt) * 64 + lane) * 8;
            *reinterpret_cast<uint4*>(XrF + o) = *reinterpret_cast<uint4*>(orw);
            *reinterpret_cast<uint4*>(XhF + o) = *reinterpret_cast<uint4*>(oh);
        }
        #pragma unroll
        for (int rep = 0; rep < 2; ++rep) {
            int idx = t + rep * 256;
            int cl = (idx >> 6) & 1, tl = idx >> 7;
            int rl = tl * 16 + (lane & 15);
            int dl = cl * 32 + (lane >> 4) * 8;
            float m = mu_s[rl], rs = rs_s[rl];
            ushort_t o8[8];
            #pragma unroll
            for (int j = 0; j < 8; ++j)
                o8[j] = f2bf((tile[rl][dl + j] - m) * rs);
            size_t o = (((size_t)(rbase >> 4) + tl) * 24 + (d0 >> 5) + cl) * 512 + lane * 8;
            *reinterpret_cast<uint4*>(AF + o) = *reinterpret_cast<uint4*>(o8);
        }
        return;
    }
    // t-projection sgemm: t = LN(lat)@(g*W)+bias, split-K atomics
    {
        int f = bid - 1152;
        int bx = f % 4, by = (f / 4) % 2, z = f / 8;   // z in 0..11, nz0=6
        int cfg = (z >= 6) ? 1 : 0;
        int kz = cfg ? z - 6 : z;
        sgemm_body(smem, t,
                   lat, cfg ? i_tp_w : t_tp_w, cfg ? i_tn_g : t_tn_g,
                   cfg ? b_tp_i : b_tp_t, mu, rstd, 6144,
                   cfg ? t_i : t_t, kz, bx, by, D_, E_);
    }
}

// ===========================================================================
// stage3: c2-gemm (32) + sproj (192) + pack_M (8192) = 8416 blocks.
// dyn LDS 18432 B. Small blocks first so they overlap pack_M's long dispatch.
// ===========================================================================
__global__ __launch_bounds__(256) void stage3_kernel(
    const float* __restrict__ t_t, const float* __restrict__ t_i,
    const float* __restrict__ t_m1_w, const float* __restrict__ t_m1_b,
    const float* __restrict__ i_m1_w, const float* __restrict__ i_m1_b,
    float* __restrict__ c2_t, float* __restrict__ c2_i,
    const ushort_t* __restrict__ AF_t, const ushort_t* __restrict__ BF_t,
    const float* __restrict__ b_su_t, ushort_t* __restrict__ sF_t,
    const ushort_t* __restrict__ AF_i, const ushort_t* __restrict__ BF_i,
    const float* __restrict__ b_su_i, ushort_t* __restrict__ sF_i,
    ushort_t* __restrict__ MF_t, ushort_t* __restrict__ MF_i)
{
    extern __shared__ __align__(16) char smem[];
    int bid = blockIdx.x;
    int tid = threadIdx.x;
    if (bid < 32) {
        // c2 = t @ W2 + m1_b
        int bx = bid % 4, by = (bid / 4) % 2, z = bid / 8;  // z 0..3, nz0=2
        int cfg = (z >= 2) ? 1 : 0;
        int kz = cfg ? z - 2 : z;
        sgemm_body(smem, tid,
                   cfg ? t_i : t_t,
                   (cfg ? i_m1_w : t_m1_w) + (size_t)E_ * E_, nullptr,
                   cfg ? i_m1_b : t_m1_b, nullptr, nullptr, 0,
                   cfg ? c2_i : c2_t, kz, bx, by, E_, E_);
        return;
    }
    if (bid < 224) {
        // sproj: s = xhat@Wf + bias -> sF A-frags
        int bx = bid - 32;
        int isImg = bx >= 128;
        const ushort_t* AF = isImg ? AF_i : AF_t;
        const ushort_t* BF = isImg ? BF_i : BF_t;
        const float* bias = isImg ? b_su_i : b_su_t;
        ushort_t* sF = isImg ? sF_i : sF_t;
        int tile0 = (isImg ? bx - 128 : bx) * 2;
        ushort_t* lsbase = (ushort_t*)smem;   // [4*32][72]
        int w = tid >> 6, lane = tid & 63;
        int quad = lane >> 4, n16 = lane & 15;
        f32x4 acc[2][4];
        #pragma unroll
        for (int mt = 0; mt < 2; ++mt)
            #pragma unroll
            for (int nt = 0; nt < 4; ++nt)
                acc[mt][nt] = (f32x4){0.f, 0.f, 0.f, 0.f};
        for (int c = 0; c < 24; ++c) {
            bf16x8 af[2], bf[4];
            #pragma unroll
            for (int mt = 0; mt < 2; ++mt)
                af[mt] = *reinterpret_cast<const bf16x8*>(AF + ((size_t)(tile0 + mt) * 24 + c) * 512 + lane * 8);
            #pragma unroll
            for (int nt = 0; nt < 4; ++nt)
                bf[nt] = *reinterpret_cast<const bf16x8*>(BF + ((size_t)c * 16 + w * 4 + nt) * 512 + lane * 8);
            #pragma unroll
            for (int mt = 0; mt < 2; ++mt)
                #pragma unroll
                for (int nt = 0; nt < 4; ++nt)
                    acc[mt][nt] = __builtin_amdgcn_mfma_f32_16x16x32_bf16(af[mt], bf[nt], acc[mt][nt], 0, 0, 0);
        }
        #pragma unroll
        for (int mt = 0; mt < 2; ++mt)
            #pragma unroll
            for (int nt = 0; nt < 4; ++nt) {
                float bv = bias[w * 64 + nt * 16 + n16];
                #pragma unroll
                for (int r = 0; r < 4; ++r)
                    lsbase[(w * 32 + mt * 16 + quad * 4 + r) * 72 + nt * 16 + n16] = f2bf(acc[mt][nt][r] + bv);
            }
        __syncthreads();
        #pragma unroll
        for (int mt = 0; mt < 2; ++mt)
            #pragma unroll
            for (int h = 0; h < 2; ++h) {
                uint4 v = *reinterpret_cast<const uint4*>(&lsbase[(w * 32 + mt * 16 + n16) * 72 + h * 32 + quad * 8]);
                *reinterpret_cast<uint4*>(sF + ((size_t)(tile0 + mt) * 8 + 2 * w + h) * 512 + lane * 8) = v;
            }
        return;
    }
    // pack_M: M_k = t[k,e]*W3[e,j] + W1[e,j]
    {
        const int HALF = B_ * K_ * 16 * 8 * 64;   // 1048576
        int gidx = (bid - 224) * 256 + tid;
        int isImg = gidx >= HALF;
        int idx = isImg ? gidx - HALF : gidx;
        const float* tP = isImg ? t_i : t_t;
        const float* W3 = (isImg ? i_m1_w : t_m1_w) + 2 * (size_t)E_ * E_;
        const float* W1 = isImg ? i_m1_w : t_m1_w;
        ushort_t* MF = isImg ? MF_i : MF_t;
        int lane = idx & 63;
        int kc = (idx >> 6) & 7;
        int nt = (idx >> 9) & 15;
        int bk = idx >> 13;
        int n = nt * 16 + (lane & 15);
        int e0 = kc * 32 + (lane >> 4) * 8;
        ushort_t out[8];
        #pragma unroll
        for (int j = 0; j < 8; ++j) {
            int e = e0 + j;
            float v = tP[(size_t)bk * E_ + e] * W3[(size_t)e * E_ + n] + W1[(size_t)e * E_ + n];
            out[j] = f2bf(v);
        }
        *reinterpret_cast<uint4*>(MF + (size_t)idx * 8) = *reinterpret_cast<uint4*>(out);
    }
}

// ===========================================================================
// Cross + edge via MFMA. grid (K=64, 96, B), k fastest; 32-row s-tiles.
// launch_bounds(256,5): acc 2x4 (32 AGPR) + ~60 VGPR fits the 102-reg cap.
// R6/R11 lessons: accumulators init to zero; never exceed the reg cap.
// Epilogue: z = acc + c2; gelu = z*sigmoid(1.702z) via raw v_exp_f32.
// Etmp write = 32 floats = one aligned 128 B line per block.
// ===========================================================================
__global__ __launch_bounds__(256, 5) void cross_mfma_kernel(
    const ushort_t* __restrict__ sF_t, const ushort_t* __restrict__ MF_t,
    const float* __restrict__ c2_t, const float* __restrict__ m2w_t,
    const float* __restrict__ m2b_t, const float* __restrict__ mask_t,
    float* __restrict__ Et,
    const ushort_t* __restrict__ sF_i, const ushort_t* __restrict__ MF_i,
    const float* __restrict__ c2_i, const float* __restrict__ m2w_i,
    const float* __restrict__ m2b_i, const float* __restrict__ mask_i,
    float* __restrict__ Ei)
{
    int k = blockIdx.x;
    int by = blockIdx.y;
    int isImg = by >= 64;
    int S = isImg ? SI_ : ST_;
    const ushort_t* sF = isImg ? sF_i : sF_t;
    const ushort_t* MF = isImg ? MF_i : MF_t;
    const float* c2P = isImg ? c2_i : c2_t;
    const float* m2w = isImg ? m2w_i : m2w_t;
    const float* m2b = isImg ? m2b_i : m2b_t;
    const float* mask = isImg ? mask_i : mask_t;
    float* Etmp = isImg ? Ei : Et;
    int s0 = (isImg ? by - 64 : by) * 32;
    int b = blockIdx.z;
    int tid = threadIdx.x;
    int w = tid >> 6, lane = tid & 63;
    int quad = lane >> 4, n16 = lane & 15;

    const ushort_t* aBase = sF + (size_t)(b * (S / 16) + (s0 >> 4)) * 4096;
    const ushort_t* bBase = MF + ((size_t)(b * K_ + k) * 16 + w * 4) * 4096;

    f32x4 acc[2][4];
    #pragma unroll
    for (int mt = 0; mt < 2; ++mt)
        #pragma unroll
        for (int nt = 0; nt < 4; ++nt)
            acc[mt][nt] = (f32x4){0.f, 0.f, 0.f, 0.f};

    #pragma unroll
    for (int kc = 0; kc < 8; ++kc) {
        bf16x8 bfr[4], af[2];
        #pragma unroll
        for (int nt = 0; nt < 4; ++nt)
            bfr[nt] = *reinterpret_cast<const bf16x8*>(bBase + (size_t)nt * 4096 + kc * 512 + lane * 8);
        #pragma unroll
        for (int mt = 0; mt < 2; ++mt)
            af[mt] = *reinterpret_cast<const bf16x8*>(aBase + (size_t)mt * 4096 + kc * 512 + lane * 8);
        #pragma unroll
        for (int mt = 0; mt < 2; ++mt)
            #pragma unroll
            for (int nt = 0; nt < 4; ++nt)
                acc[mt][nt] = __builtin_amdgcn_mfma_f32_16x16x32_bf16(af[mt], bfr[nt], acc[mt][nt], 0, 0, 0);
    }

    const float* c2v = c2P + (size_t)(b * K_ + k) * E_;
    float c2r[4], m2r[4];
    #pragma unroll
    for (int nt = 0; nt < 4; ++nt) {
        int col = w * 64 + nt * 16 + n16;
        c2r[nt] = c2v[col];
        m2r[nt] = m2w[col];
    }
    __shared__ float pPart[4][32];
    #pragma unroll
    for (int mt = 0; mt < 2; ++mt) {
        #pragma unroll
        for (int r = 0; r < 4; ++r) {
            float p = 0.f;
            #pragma unroll
            for (int nt = 0; nt < 4; ++nt) {
                float z = acc[mt][nt][r] + c2r[nt];
                // sigmoid-gelu: m2*z*sigmoid(1.702z); -1.702*log2(e) = -2.4554670
                float u = z * -2.4554670f;
                float t;
                asm("v_exp_f32 %0, %1" : "=v"(t) : "v"(u));
                float sg = __builtin_amdgcn_rcpf(1.0f + t);
                p = fmaf(m2r[nt] * z, sg, p);
            }
            p += __shfl_xor(p, 1, 64);
            p += __shfl_xor(p, 2, 64);
            p += __shfl_xor(p, 4, 64);
            p += __shfl_xor(p, 8, 64);
            if (n16 == 0) pPart[w][mt * 16 + quad * 4 + r] = p;
        }
    }
    __syncthreads();
    if (tid < 32) {
        float e = pPart[0][tid] + pPart[1][tid] + pPart[2][tid] + pPart[3][tid] + m2b[0];
        e = e / (1.0f + fabsf(e));
        int srow = s0 + tid;
        e *= mask[(size_t)b * S + srow];
        Etmp[(size_t)(b * K_ + k) * S + srow] = e;   // one aligned 128 B line
    }
}

// ===========================================================================
// packE2: read Etmp[b][k][s] coalesced; write t2l/i2l, EF A-frags, rowsum.
// ===========================================================================
__global__ __launch_bounds__(256) void packE2_kernel(
    const float* __restrict__ Et, const float* __restrict__ Ei,
    float* __restrict__ t2l, float* __restrict__ i2l,
    ushort_t* __restrict__ EF_t, ushort_t* __restrict__ EF_i,
    float* __restrict__ rs_t, float* __restrict__ rs_i)
{
    __shared__ float tile[64][33];   // [k][s]
    int g = blockIdx.x;
    int isImg = g >= 128;
    const float* Esrc = isImg ? Ei : Et;
    float* dst = isImg ? i2l : t2l;
    ushort_t* EF = isImg ? EF_i : EF_t;
    float* rsum = isImg ? rs_i : rs_t;
    int chunk = isImg ? g - 128 : g;
    int S = isImg ? SI_ : ST_;
    int b = (chunk * 32) / S;
    int s0 = (chunk * 32) % S;
    int t = threadIdx.x;
    {
        int k = t >> 2, si = (t & 3) * 8;
        const float* p = Esrc + (size_t)(b * K_ + k) * S + s0 + si;
        *(float4*)&tile[k][si] = *(const float4*)p;
        *(float4*)&tile[k][si + 4] = *(const float4*)(p + 4);
    }
    __syncthreads();
    {
        int s = t >> 3, k0 = (t & 7) * 8;
        float o[8];
        #pragma unroll
        for (int j = 0; j < 8; ++j) o[j] = tile[k0 + j][s];
        float* p = dst + ((size_t)b * S + s0 + s) * K_ + k0;
        *(float4*)p = *(float4*)&o[0];
        *(float4*)(p + 4) = *(float4*)&o[4];
    }
    {
        int mt = t >> 6, lane = t & 63;
        int k = mt * 16 + (lane & 15);
        int sl0 = (lane >> 4) * 8;
        ushort_t o8[8];
        #pragma unroll
        for (int j = 0; j < 8; ++j)
            o8[j] = f2bf(tile[k][sl0 + j]);
        *reinterpret_cast<uint4*>(EF + (((size_t)chunk * 4 + mt) * 64 + lane) * 8) = *reinterpret_cast<uint4*>(o8);
    }
    if (t < 64) {
        float s = 0.f;
        #pragma unroll
        for (int j = 0; j < 32; ++j) s += tile[t][j];
        atomicAdd(&rsum[b * K_ + t], s);
    }
}

// ===========================================================================
// einsum via MFMA. grid (6, 16, 4): bz<2 text (b=bz), else image. nt=2/wave.
// ===========================================================================
__global__ __launch_bounds__(256, 4) void einsum_mfma_kernel(
    const ushort_t* __restrict__ EF_t, const ushort_t* __restrict__ XhF_t,
    const ushort_t* __restrict__ XrF_t, float* __restrict__ PtG, float* __restrict__ PtR,
    const ushort_t* __restrict__ EF_i, const ushort_t* __restrict__ XhF_i,
    const ushort_t* __restrict__ XrF_i, float* __restrict__ PiG, float* __restrict__ PiR)
{
    int bz = blockIdx.z;
    int isImg = bz >= 2;
    int b = isImg ? bz - 2 : bz;
    int S = isImg ? SI_ : ST_;
    const ushort_t* EF = isImg ? EF_i : EF_t;
    const ushort_t* XhF = isImg ? XhF_i : XhF_t;
    const ushort_t* XrF = isImg ? XrF_i : XrF_t;
    float* PG = isImg ? PiG : PtG;
    float* PR = isImg ? PiR : PtR;
    int chunksPerBlock = isImg ? 2 : 4;

    int w = threadIdx.x >> 6, lane = threadIdx.x & 63;
    int quad = lane >> 4, n16 = lane & 15;
    int y = blockIdx.y;
    int nt0 = blockIdx.x * 8 + w * 2;
    size_t cb = (size_t)(b * S) / 32 + (size_t)y * chunksPerBlock;

    f32x4 aG[4][2], aR[4][2];
    #pragma unroll
    for (int mt = 0; mt < 4; ++mt)
        #pragma unroll
        for (int nt = 0; nt < 2; ++nt) {
            aG[mt][nt] = (f32x4){0.f, 0.f, 0.f, 0.f};
            aR[mt][nt] = (f32x4){0.f, 0.f, 0.f, 0.f};
        }

    for (int cc = 0; cc < chunksPerBlock; ++cc) {
        size_t c = cb + cc;
        bf16x8 af[4], bh[2], bx[2];
        #pragma unroll
        for (int mt = 0; mt < 4; ++mt)
            af[mt] = *reinterpret_cast<const bf16x8*>(EF + ((c * 4 + mt) * 64 + lane) * 8);
        #pragma unroll
        for (int nt = 0; nt < 2; ++nt) {
            bh[nt] = *reinterpret_cast<const bf16x8*>(XhF + ((c * 48 + nt0 + nt) * 64 + lane) * 8);
            bx[nt] = *reinterpret_cast<const bf16x8*>(XrF + ((c * 48 + nt0 + nt) * 64 + lane) * 8);
        }
        #pragma unroll
        for (int mt = 0; mt < 4; ++mt)
            #pragma unroll
            for (int nt = 0; nt < 2; ++nt) {
                aG[mt][nt] = __builtin_amdgcn_mfma_f32_16x16x32_bf16(af[mt], bh[nt], aG[mt][nt], 0, 0, 0);
                aR[mt][nt] = __builtin_amdgcn_mfma_f32_16x16x32_bf16(af[mt], bx[nt], aR[mt][nt], 0, 0, 0);
            }
    }
    #pragma unroll
    for (int mt = 0; mt < 4; ++mt)
        #pragma unroll
        for (int nt = 0; nt < 2; ++nt) {
            int d = (nt0 + nt) * 16 + n16;
            #pragma unroll
            for (int r = 0; r < 4; ++r) {
                int krow = mt * 16 + quad * 4 + r;
                size_t o = (((size_t)y * B_ + b) * K_ + krow) * D_ + d;
                PG[o] = aG[mt][nt][r];
                PR[o] = aR[mt][nt][r];
            }
        }
}

// ---------------------------------------------------------------------------
__global__ __launch_bounds__(256) void reduce_parts_kernel(
    const float* __restrict__ PtG, const float* __restrict__ PtR,
    const float* __restrict__ PiG, const float* __restrict__ PiR,
    float* __restrict__ Gt, float* __restrict__ Gi, float* __restrict__ Racc)
{
    const int BKD = B_ * K_ * D_;
    int idx = blockIdx.x * 256 + threadIdx.x;
    if (idx >= BKD) return;
    float gt = 0.f, gi = 0.f, r = 0.f;
    #pragma unroll
    for (int c = 0; c < 16; ++c) { gt += PtG[(size_t)c * BKD + idx]; r += PtR[(size_t)c * BKD + idx]; }
    #pragma unroll
    for (int c = 0; c < 16; ++c) { gi += PiG[(size_t)c * BKD + idx]; r += PiR[(size_t)c * BKD + idx]; }
    Gt[idx] = gt; Gi[idx] = gi; Racc[idx] = r;
}

// ---------------------------------------------------------------------------
// sgemm3: state_tmp = Gt@(g*tsp_w) + Gi@(g*isp_w), split-K atomics.
// grid flat 288, dyn LDS 8256 B
// ---------------------------------------------------------------------------
__global__ __launch_bounds__(256) void sgemm3_kernel(
    const float* __restrict__ Gt, const float* __restrict__ tsp_w, const float* __restrict__ tsn_g,
    const float* __restrict__ Gi, const float* __restrict__ isp_w, const float* __restrict__ isn_g,
    float* __restrict__ state_tmp)
{
    extern __shared__ __align__(16) char smem[];
    int f = blockIdx.x;
    int bx = f % 12, by = (f / 12) % 2, z = f / 24;  // z 0..11, nz0=6
    int cfg = (z >= 6) ? 1 : 0;
    int kz = cfg ? z - 6 : z;
    sgemm_body(smem, threadIdx.x,
               cfg ? Gi : Gt, cfg ? isp_w : tsp_w, cfg ? isn_g : tsn_g,
               nullptr, nullptr, nullptr, 0, state_tmp, kz, bx, by, D_, D_);
}

// ---------------------------------------------------------------------------
__global__ __launch_bounds__(256) void final_ln_kernel(
    const float* __restrict__ stateTmp, const float* __restrict__ Racc,
    const float* __restrict__ rs_t, const float* __restrict__ rs_i,
    const float* __restrict__ b_tspf, const float* __restrict__ b_ispf,
    const float* __restrict__ state_init, const float* __restrict__ value_init,
    const float* __restrict__ stn_g, const float* __restrict__ stn_b,
    const float* __restrict__ vn_g, const float* __restrict__ vn_b,
    float* __restrict__ outState, float* __restrict__ outValue)
{
    __shared__ float pre[D_];
    __shared__ float red[256];
    int idx = blockIdx.x;
    int row = idx & 127;
    int isVal = idx >> 7;
    int tid = threadIdx.x;
    if (!isVal) {
        float rt = rs_t[row], ri = rs_i[row];
        for (int d = tid; d < D_; d += 256)
            pre[d] = stateTmp[(size_t)row * D_ + d] + rt * b_tspf[d] + ri * b_ispf[d]
                   + state_init[(size_t)row * D_ + d];
    } else {
        for (int d = tid; d < D_; d += 256)
            pre[d] = Racc[(size_t)row * D_ + d] + value_init[(size_t)row * D_ + d];
    }
    __syncthreads();
    float s = 0.f;
    for (int d = tid; d < D_; d += 256) s += pre[d];
    red[tid] = s; __syncthreads();
    for (int off = 128; off > 0; off >>= 1) { if (tid < off) red[tid] += red[tid + off]; __syncthreads(); }
    float mu = red[0] / (float)D_;
    __syncthreads();
    float v = 0.f;
    for (int d = tid; d < D_; d += 256) { float t = pre[d] - mu; v += t * t; }
    red[tid] = v; __syncthreads();
    for (int off = 128; off > 0; off >>= 1) { if (tid < off) red[tid] += red[tid + off]; __syncthreads(); }
    float rstd = rsqrtf(red[0] / (float)D_ + EPS_LN);
    const float* g  = isVal ? vn_g : stn_g;
    const float* bb = isVal ? vn_b : stn_b;
    float* o = (isVal ? outValue : outState) + (size_t)row * D_;
    for (int d = tid; d < D_; d += 256) o[d] = (pre[d] - mu) * rstd * g[d] + bb[d];
}

// ---------------------------------------------------------------------------
extern "C" void kernel_launch(void* const* d_in, const int* in_sizes, int n_in,
                              void* d_out, int out_size, void* d_ws, size_t ws_size,
                              hipStream_t stream) {
    const float* text_values  = (const float*)d_in[0];
    const float* image_values = (const float*)d_in[1];
    const float* lstate_init  = (const float*)d_in[2];
    const float* lvalue_init  = (const float*)d_in[3];
    const float* text_mask    = (const float*)d_in[4];
    const float* image_mask   = (const float*)d_in[5];
    const float* t_sn_g = (const float*)d_in[6];
    const float* t_sn_b = (const float*)d_in[7];
    const float* t_tn_g = (const float*)d_in[8];
    const float* t_tn_b = (const float*)d_in[9];
    const float* t_su_w = (const float*)d_in[10];
    const float* t_su_b = (const float*)d_in[11];
    const float* t_tp_w = (const float*)d_in[12];
    const float* t_tp_b = (const float*)d_in[13];
    const float* t_m1_w = (const float*)d_in[14];
    const float* t_m1_b = (const float*)d_in[15];
    const float* t_m2_w = (const float*)d_in[16];
    const float* t_m2_b = (const float*)d_in[17];
    const float* i_sn_g = (const float*)d_in[18];
    const float* i_sn_b = (const float*)d_in[19];
    const float* i_tn_g = (const float*)d_in[20];
    const float* i_tn_b = (const float*)d_in[21];
    const float* i_su_w = (const float*)d_in[22];
    const float* i_su_b = (const float*)d_in[23];
    const float* i_tp_w = (const float*)d_in[24];
    const float* i_tp_b = (const float*)d_in[25];
    const float* i_m1_w = (const float*)d_in[26];
    const float* i_m1_b = (const float*)d_in[27];
    const float* i_m2_w = (const float*)d_in[28];
    const float* i_m2_b = (const float*)d_in[29];
    const float* tsn_g = (const float*)d_in[30];
    const float* tsn_b = (const float*)d_in[31];
    const float* isn_g = (const float*)d_in[32];
    const float* isn_b = (const float*)d_in[33];
    const float* stn_g = (const float*)d_in[34];
    const float* stn_b = (const float*)d_in[35];
    const float* vn_g  = (const float*)d_in[36];
    const float* vn_b  = (const float*)d_in[37];
    const float* tsp_w = (const float*)d_in[38];
    const float* tsp_b = (const float*)d_in[39];
    const float* isp_w = (const float*)d_in[40];
    const float* isp_b = (const float*)d_in[41];

    float* ws = (float*)d_ws;
    size_t o = 0;
    float* stats_mu = ws + o; o += 6272;
    float* stats_rs = ws + o; o += 6272;
    // --- zeroed block (contiguous) ---
    float* zeroBase = ws + o;
    float* b_su_t = ws + o; o += E_;
    float* b_su_i = ws + o; o += E_;
    float* b_tp_t = ws + o; o += E_;
    float* b_tp_i = ws + o; o += E_;
    float* b_tspf = ws + o; o += D_;
    float* b_ispf = ws + o; o += D_;
    float* t_t  = ws + o; o += (size_t)B_ * K_ * E_;
    float* t_i  = ws + o; o += (size_t)B_ * K_ * E_;
    float* c2_t = ws + o; o += (size_t)B_ * K_ * E_;
    float* c2_i = ws + o; o += (size_t)B_ * K_ * E_;
    float* state_tmp = ws + o; o += (size_t)B_ * K_ * D_;
    float* rs_t = ws + o; o += 128;
    float* rs_i = ws + o; o += 128;
    size_t zeroFloats = (size_t)(4 * E_ + 2 * D_ + 4 * B_ * K_ * E_ + B_ * K_ * D_ + 256);
    // --- end zeroed block ---
    float* Etmp_t = ws + o; o += (size_t)B_ * K_ * ST_;
    float* Etmp_i = ws + o; o += (size_t)B_ * K_ * SI_;
    ushort_t* AF_t = (ushort_t*)(ws + o); o += (size_t)B_ * ST_ * D_ / 2;
    ushort_t* AF_i = (ushort_t*)(ws + o); o += (size_t)B_ * SI_ * D_ / 2;
    ushort_t* WsuF_t = (ushort_t*)(ws + o); o += (size_t)D_ * E_ / 2;
    ushort_t* WsuF_i = (ushort_t*)(ws + o); o += (size_t)D_ * E_ / 2;
    ushort_t* sF_t = (ushort_t*)(ws + o); o += (size_t)B_ * ST_ * E_ / 2;
    ushort_t* sF_i = (ushort_t*)(ws + o); o += (size_t)B_ * SI_ * E_ / 2;
    ushort_t* MF_t = (ushort_t*)(ws + o); o += (size_t)B_ * K_ * E_ * E_ / 2;
    ushort_t* MF_i = (ushort_t*)(ws + o); o += (size_t)B_ * K_ * E_ * E_ / 2;
    ushort_t* XhF_t = (ushort_t*)(ws + o); o += (size_t)B_ * ST_ * D_ / 2;
    ushort_t* XhF_i = (ushort_t*)(ws + o); o += (size_t)B_ * SI_ * D_ / 2;
    ushort_t* XrF_t = (ushort_t*)(ws + o); o += (size_t)B_ * ST_ * D_ / 2;
    ushort_t* XrF_i = (ushort_t*)(ws + o); o += (size_t)B_ * SI_ * D_ / 2;
    ushort_t* EF_t  = (ushort_t*)(ws + o); o += (size_t)B_ * ST_ * K_ / 2;
    ushort_t* EF_i  = (ushort_t*)(ws + o); o += (size_t)B_ * SI_ * K_ / 2;
    const int BKD = B_ * K_ * D_;
    float* PtG = ws + o; o += (size_t)16 * BKD;
    float* PtR = ws + o; o += (size_t)16 * BKD;
    float* PiG = ws + o; o += (size_t)16 * BKD;
    float* PiR = ws + o; o += (size_t)16 * BKD;
    float* Gt   = ws + o; o += BKD;
    float* Gi   = ws + o; o += BKD;
    float* Racc = ws + o; o += BKD;

    float* outState = (float*)d_out;
    float* outValue = (float*)d_out + (size_t)B_ * K_ * D_;
    float* t2l = (float*)d_out + 2 * (size_t)B_ * K_ * D_;
    float* i2l = t2l + (size_t)B_ * ST_ * K_;

    hipMemsetAsync(zeroBase, 0, zeroFloats * sizeof(float), stream);

    prelude_kernel<<<2624, 256, 1024, stream>>>(
        text_values, image_values, lvalue_init, stats_mu, stats_rs,
        t_sn_b, t_su_w, t_su_b, b_su_t,
        i_sn_b, i_su_w, i_su_b, b_su_i,
        t_tn_b, t_tp_w, t_tp_b, b_tp_t,
        i_tn_b, i_tp_w, i_tp_b, b_tp_i,
        tsn_b, tsp_w, tsp_b, b_tspf,
        isn_b, isp_w, isp_b, b_ispf,
        t_su_w, t_sn_g, WsuF_t,
        i_su_w, i_sn_g, WsuF_i);

    stage2_kernel<<<1248, 256, 17152, stream>>>(
        text_values, image_values, stats_mu, stats_rs,
        XrF_t, XhF_t, AF_t, XrF_i, XhF_i, AF_i,
        lvalue_init,
        t_tp_w, t_tn_g, b_tp_t, t_t,
        i_tp_w, i_tn_g, b_tp_i, t_i);

    stage3_kernel<<<8416, 256, 18432, stream>>>(
        t_t, t_i, t_m1_w, t_m1_b, i_m1_w, i_m1_b, c2_t, c2_i,
        AF_t, WsuF_t, b_su_t, sF_t,
        AF_i, WsuF_i, b_su_i, sF_i,
        MF_t, MF_i);

    cross_mfma_kernel<<<dim3(K_, 96, B_), 256, 0, stream>>>(
        sF_t, MF_t, c2_t, t_m2_w, t_m2_b, text_mask, Etmp_t,
        sF_i, MF_i, c2_i, i_m2_w, i_m2_b, image_mask, Etmp_i);

    packE2_kernel<<<192, 256, 0, stream>>>(
        Etmp_t, Etmp_i, t2l, i2l, EF_t, EF_i, rs_t, rs_i);

    einsum_mfma_kernel<<<dim3(6, 16, 4), 256, 0, stream>>>(
        EF_t, XhF_t, XrF_t, PtG, PtR,
        EF_i, XhF_i, XrF_i, PiG, PiR);

    reduce_parts_kernel<<<(BKD + 255) / 256, 256, 0, stream>>>(PtG, PtR, PiG, PiR, Gt, Gi, Racc);

    sgemm3_kernel<<<288, 256, 8256, stream>>>(
        Gt, tsp_w, tsn_g, Gi, isp_w, isn_g, state_tmp);

    final_ln_kernel<<<2 * B_ * K_, 256, 0, stream>>>(
        state_tmp, Racc, rs_t, rs_i, b_tspf, b_ispf,
        lstate_init, lvalue_init, stn_g, stn_b, vn_g, vn_b, outState, outValue);
}

// Round 15
// 315.922 us; speedup vs baseline: 1.0487x; 1.0471x over previous
//
#include <hip/hip_runtime.h>
#include <math.h>

#define EPS_LN 1e-5f

#define B_  2
#define ST_ 2048
#define SI_ 1024
#define K_  64
#define D_  768
#define E_  256

typedef __bf16 bf16x8 __attribute__((ext_vector_type(8)));
typedef float  f32x4  __attribute__((ext_vector_type(4)));
typedef unsigned short ushort_t;

__device__ inline ushort_t f2bf(float x) {
    unsigned int u = __float_as_uint(x);
    unsigned int r = (u + 0x7FFFu + ((u >> 16) & 1u)) >> 16;
    return (ushort_t)r;
}

// ===========================================================================
// Device bodies for fused kernels
// ===========================================================================

__device__ void ln_stats_body(int bid, int tid,
    const float* __restrict__ xt, const float* __restrict__ xi,
    const float* __restrict__ xl, float* __restrict__ mu, float* __restrict__ rstd)
{
    int w = tid >> 6, lane = tid & 63;
    int row = bid * 4 + w;
    const float* src;
    if (row < 4096) src = xt + (size_t)row * D_;
    else if (row < 6144) src = xi + (size_t)(row - 4096) * D_;
    else src = xl + (size_t)(row - 6144) * D_;
    float s = 0.f, q = 0.f;
    #pragma unroll
    for (int rep = 0; rep < 3; ++rep) {
        float4 v = *(const float4*)(src + lane * 4 + rep * 256);
        s += v.x + v.y + v.z + v.w;
        q += v.x * v.x + v.y * v.y + v.z * v.z + v.w * v.w;
    }
    #pragma unroll
    for (int off = 32; off > 0; off >>= 1) {
        s += __shfl_xor(s, off, 64);
        q += __shfl_xor(q, off, 64);
    }
    if (lane == 0) {
        float m = s / (float)D_;
        float var = q / (float)D_ - m * m;
        mu[row] = m;
        rstd[row] = rsqrtf(var + EPS_LN);
    }
}

__device__ void sgemm_body(char* smem, int tid,
    const float* __restrict__ A, const float* __restrict__ Bm,
    const float* __restrict__ rowScale, const float* __restrict__ bias,
    const float* __restrict__ muA, const float* __restrict__ sdA, int so,
    float* __restrict__ C, int kz, int bx, int by, int Kd, int N)
{
    float (*As)[65] = (float(*)[65])smem;
    float (*Bs)[64] = (float(*)[64])(smem + 16 * 65 * 4);
    int tx = tid & 15, ty = tid >> 4;
    int row0 = by * 64;
    int col0 = bx * 64;
    float acc[4][4] = {};
    int kbase = kz * 128;
    for (int k0 = kbase; k0 < kbase + 128; k0 += 16) {
        {
            int e = tid * 4;
            int r = e >> 4, kk = e & 15;
            float4 av = *(const float4*)(A + (size_t)(row0 + r) * Kd + k0 + kk);
            if (muA) {
                float m = muA[so + row0 + r], sd = sdA[so + row0 + r];
                av.x = (av.x - m) * sd; av.y = (av.y - m) * sd;
                av.z = (av.z - m) * sd; av.w = (av.w - m) * sd;
            }
            As[kk + 0][r] = av.x; As[kk + 1][r] = av.y; As[kk + 2][r] = av.z; As[kk + 3][r] = av.w;
        }
        {
            int e = tid * 4;
            int kk = e >> 6, c = e & 63;
            float4 bv = *(const float4*)(Bm + (size_t)(k0 + kk) * N + col0 + c);
            if (rowScale) {
                float sc = rowScale[k0 + kk];
                bv.x *= sc; bv.y *= sc; bv.z *= sc; bv.w *= sc;
            }
            *(float4*)&Bs[kk][c] = bv;
        }
        __syncthreads();
        #pragma unroll
        for (int kk = 0; kk < 16; ++kk) {
            float a[4], b[4];
            #pragma unroll
            for (int i = 0; i < 4; ++i) a[i] = As[kk][ty + 16 * i];
            #pragma unroll
            for (int j = 0; j < 4; ++j) b[j] = Bs[kk][tx + 16 * j];
            #pragma unroll
            for (int i = 0; i < 4; ++i)
                #pragma unroll
                for (int j = 0; j < 4; ++j)
                    acc[i][j] += a[i] * b[j];
        }
        __syncthreads();
    }
    #pragma unroll
    for (int i = 0; i < 4; ++i) {
        int r = row0 + ty + 16 * i;
        #pragma unroll
        for (int j = 0; j < 4; ++j) {
            int c = col0 + tx + 16 * j;
            float v = acc[i][j];
            if (kz == 0 && bias) v += bias[c];
            atomicAdd(&C[(size_t)r * N + c], v);
        }
    }
}

// ===========================================================================
// prelude: ln_stats (1568) + fold_all (864) + packB2 (192) = 2624 blocks
// dyn LDS: 1024 B
// ===========================================================================
__global__ __launch_bounds__(256) void prelude_kernel(
    const float* __restrict__ xt, const float* __restrict__ xi,
    const float* __restrict__ xl, float* __restrict__ mu, float* __restrict__ rstd,
    const float* b0, const float* W0, const float* w0, float* f0,
    const float* b1, const float* W1, const float* w1, float* f1,
    const float* b2, const float* W2, const float* w2, float* f2,
    const float* b3, const float* W3, const float* w3, float* f3,
    const float* b4, const float* W4, const float* w4, float* f4,
    const float* b5, const float* W5, const float* w5, float* f5,
    const float* __restrict__ Wsu_t, const float* __restrict__ g_t, ushort_t* __restrict__ WF_t,
    const float* __restrict__ Wsu_i, const float* __restrict__ g_i, ushort_t* __restrict__ WF_i)
{
    extern __shared__ __align__(16) char smem[];
    int bid = blockIdx.x;
    int tid = threadIdx.x;
    if (bid < 1568) {
        ln_stats_body(bid, tid, xt, xi, xl, mu, rstd);
        return;
    }
    if (bid < 2432) {
        // fold_all
        int f = bid - 1568;
        int ebx = f % 12, dby = (f / 12) % 12, cfg = f / 144;
        const float* blns[6] = {b0, b1, b2, b3, b4, b5};
        const float* Ws[6]   = {W0, W1, W2, W3, W4, W5};
        const float* wbs[6]  = {w0, w1, w2, w3, w4, w5};
        float* bfs[6]        = {f0, f1, f2, f3, f4, f5};
        int E = (cfg >= 4) ? 768 : 256;
        if (ebx * 64 >= E) return;
        const float* bln = blns[cfg];
        const float* W = Ws[cfg];
        float (*red)[64] = (float(*)[64])smem;
        int c = tid & 63, part = tid >> 6;
        int e = ebx * 64 + c;
        int d0 = dby * 64;
        float s = 0.f;
        #pragma unroll
        for (int i = 0; i < 16; ++i) {
            int d = d0 + part * 16 + i;
            s += bln[d] * W[(size_t)d * E + e];
        }
        red[part][c] = s; __syncthreads();
        if (part == 0) {
            float v = red[0][c] + red[1][c] + red[2][c] + red[3][c];
            if (dby == 0 && wbs[cfg]) v += wbs[cfg][e];
            atomicAdd(&bfs[cfg][e], v);
        }
        return;
    }
    // packB2
    {
        const int HALF = (D_ >> 5) * (E_ >> 4) * 64;  // 24576
        int gidx = (bid - 2432) * 256 + tid;
        int isImg = gidx >= HALF;
        int idx = isImg ? gidx - HALF : gidx;
        const float* W = isImg ? Wsu_i : Wsu_t;
        const float* g = isImg ? g_i : g_t;
        ushort_t* out = isImg ? WF_i : WF_t;
        int lane = idx & 63;
        int ntile = (idx >> 6) & 15;
        int c = idx >> 10;
        int n = ntile * 16 + (lane & 15);
        int k0 = c * 32 + (lane >> 4) * 8;
        ushort_t o[8];
        #pragma unroll
        for (int j = 0; j < 8; ++j) {
            int k = k0 + j;
            o[j] = f2bf(W[(size_t)k * E_ + n] * g[k]);
        }
        *reinterpret_cast<uint4*>(out + (size_t)idx * 8) = *reinterpret_cast<uint4*>(o);
    }
}

// ===========================================================================
// stage2: tpack (1152) + t-proj sgemm (96) = 1248 blocks. dyn LDS 17152 B
// ===========================================================================
__global__ __launch_bounds__(256) void stage2_kernel(
    const float* __restrict__ xt, const float* __restrict__ xi,
    const float* __restrict__ mu, const float* __restrict__ rstd,
    ushort_t* __restrict__ XrF_t, ushort_t* __restrict__ XhF_t, ushort_t* __restrict__ AF_t,
    ushort_t* __restrict__ XrF_i, ushort_t* __restrict__ XhF_i, ushort_t* __restrict__ AF_i,
    const float* __restrict__ lat,
    const float* __restrict__ t_tp_w, const float* __restrict__ t_tn_g,
    const float* __restrict__ b_tp_t, float* __restrict__ t_t,
    const float* __restrict__ i_tp_w, const float* __restrict__ i_tn_g,
    const float* __restrict__ b_tp_i, float* __restrict__ t_i)
{
    extern __shared__ __align__(16) char smem[];
    int bid = blockIdx.x;
    int t = threadIdx.x;
    if (bid < 1152) {
        // tpack
        int bx = bid % 96, by = bid / 96;
        float (*tile)[65] = (float(*)[65])smem;
        float* mu_s = (float*)(smem + 64 * 65 * 4);
        float* rs_s = mu_s + 64;
        int isImg = bx >= 64;
        const float* x = isImg ? xi : xt;
        ushort_t* XrF = isImg ? XrF_i : XrF_t;
        ushort_t* XhF = isImg ? XhF_i : XhF_t;
        ushort_t* AF  = isImg ? AF_i  : AF_t;
        int rbase = (isImg ? bx - 64 : bx) * 64;
        int statOff = isImg ? 4096 : 0;
        int d0 = by * 64;
        #pragma unroll
        for (int rep = 0; rep < 4; ++rep) {
            int rl = (t >> 4) + rep * 16;
            int c4 = (t & 15) * 4;
            *(float4*)&tile[rl][c4] = *(const float4*)(x + (size_t)(rbase + rl) * D_ + d0 + c4);
        }
        if (t < 64) { mu_s[t] = mu[statOff + rbase + t]; rs_s[t] = rstd[statOff + rbase + t]; }
        __syncthreads();
        int lane = t & 63;
        #pragma unroll
        for (int rep = 0; rep < 2; ++rep) {
            int idx = t + rep * 256;
            int nt = (idx >> 6) & 3, cl = (idx >> 8) & 1;
            int kl = cl * 32 + (lane >> 4) * 8;
            int nl = nt * 16 + (lane & 15);
            ushort_t orw[8], oh[8];
            #pragma unroll
            for (int j = 0; j < 8; ++j) {
                float v = tile[kl + j][nl];
                orw[j] = f2bf(v);
                oh[j]  = f2bf((v - mu_s[kl + j]) * rs_s[kl + j]);
            }
            size_t chunk = (size_t)((rbase >> 5) + cl);
            size_t o = ((chunk * 48 + (d0 >> 4) + nt) * 64 + lane) * 8;
            *reinterpret_cast<uint4*>(XrF + o) = *reinterpret_cast<uint4*>(orw);
            *reinterpret_cast<uint4*>(XhF + o) = *reinterpret_cast<uint4*>(oh);
        }
        #pragma unroll
        for (int rep = 0; rep < 2; ++rep) {
            int idx = t + rep * 256;
            int cl = (idx >> 6) & 1, tl = idx >> 7;
            int rl = tl * 16 + (lane & 15);
            int dl = cl * 32 + (lane >> 4) * 8;
            float m = mu_s[rl], rs = rs_s[rl];
            ushort_t o8[8];
            #pragma unroll
            for (int j = 0; j < 8; ++j)
                o8[j] = f2bf((tile[rl][dl + j] - m) * rs);
            size_t o = (((size_t)(rbase >> 4) + tl) * 24 + (d0 >> 5) + cl) * 512 + lane * 8;
            *reinterpret_cast<uint4*>(AF + o) = *reinterpret_cast<uint4*>(o8);
        }
        return;
    }
    // t-projection sgemm: t = LN(lat)@(g*W)+bias, split-K atomics
    {
        int f = bid - 1152;
        int bx = f % 4, by = (f / 4) % 2, z = f / 8;   // z in 0..11, nz0=6
        int cfg = (z >= 6) ? 1 : 0;
        int kz = cfg ? z - 6 : z;
        sgemm_body(smem, t,
                   lat, cfg ? i_tp_w : t_tp_w, cfg ? i_tn_g : t_tn_g,
                   cfg ? b_tp_i : b_tp_t, mu, rstd, 6144,
                   cfg ? t_i : t_t, kz, bx, by, D_, E_);
    }
}

// ===========================================================================
// stage3: c2-gemm (32) + sproj (192) + pack_M (8192) = 8416 blocks.
// dyn LDS 18432 B. Small blocks first so they overlap pack_M's long dispatch.
// ===========================================================================
__global__ __launch_bounds__(256) void stage3_kernel(
    const float* __restrict__ t_t, const float* __restrict__ t_i,
    const float* __restrict__ t_m1_w, const float* __restrict__ t_m1_b,
    const float* __restrict__ i_m1_w, const float* __restrict__ i_m1_b,
    float* __restrict__ c2_t, float* __restrict__ c2_i,
    const ushort_t* __restrict__ AF_t, const ushort_t* __restrict__ BF_t,
    const float* __restrict__ b_su_t, ushort_t* __restrict__ sF_t,
    const ushort_t* __restrict__ AF_i, const ushort_t* __restrict__ BF_i,
    const float* __restrict__ b_su_i, ushort_t* __restrict__ sF_i,
    ushort_t* __restrict__ MF_t, ushort_t* __restrict__ MF_i)
{
    extern __shared__ __align__(16) char smem[];
    int bid = blockIdx.x;
    int tid = threadIdx.x;
    if (bid < 32) {
        // c2 = t @ W2 + m1_b
        int bx = bid % 4, by = (bid / 4) % 2, z = bid / 8;  // z 0..3, nz0=2
        int cfg = (z >= 2) ? 1 : 0;
        int kz = cfg ? z - 2 : z;
        sgemm_body(smem, tid,
                   cfg ? t_i : t_t,
                   (cfg ? i_m1_w : t_m1_w) + (size_t)E_ * E_, nullptr,
                   cfg ? i_m1_b : t_m1_b, nullptr, nullptr, 0,
                   cfg ? c2_i : c2_t, kz, bx, by, E_, E_);
        return;
    }
    if (bid < 224) {
        // sproj: s = xhat@Wf + bias -> sF A-frags
        int bx = bid - 32;
        int isImg = bx >= 128;
        const ushort_t* AF = isImg ? AF_i : AF_t;
        const ushort_t* BF = isImg ? BF_i : BF_t;
        const float* bias = isImg ? b_su_i : b_su_t;
        ushort_t* sF = isImg ? sF_i : sF_t;
        int tile0 = (isImg ? bx - 128 : bx) * 2;
        ushort_t* lsbase = (ushort_t*)smem;   // [4*32][72]
        int w = tid >> 6, lane = tid & 63;
        int quad = lane >> 4, n16 = lane & 15;
        f32x4 acc[2][4];
        #pragma unroll
        for (int mt = 0; mt < 2; ++mt)
            #pragma unroll
            for (int nt = 0; nt < 4; ++nt)
                acc[mt][nt] = (f32x4){0.f, 0.f, 0.f, 0.f};
        for (int c = 0; c < 24; ++c) {
            bf16x8 af[2], bf[4];
            #pragma unroll
            for (int mt = 0; mt < 2; ++mt)
                af[mt] = *reinterpret_cast<const bf16x8*>(AF + ((size_t)(tile0 + mt) * 24 + c) * 512 + lane * 8);
            #pragma unroll
            for (int nt = 0; nt < 4; ++nt)
                bf[nt] = *reinterpret_cast<const bf16x8*>(BF + ((size_t)c * 16 + w * 4 + nt) * 512 + lane * 8);
            #pragma unroll
            for (int mt = 0; mt < 2; ++mt)
                #pragma unroll
                for (int nt = 0; nt < 4; ++nt)
                    acc[mt][nt] = __builtin_amdgcn_mfma_f32_16x16x32_bf16(af[mt], bf[nt], acc[mt][nt], 0, 0, 0);
        }
        #pragma unroll
        for (int mt = 0; mt < 2; ++mt)
            #pragma unroll
            for (int nt = 0; nt < 4; ++nt) {
                float bv = bias[w * 64 + nt * 16 + n16];
                #pragma unroll
                for (int r = 0; r < 4; ++r)
                    lsbase[(w * 32 + mt * 16 + quad * 4 + r) * 72 + nt * 16 + n16] = f2bf(acc[mt][nt][r] + bv);
            }
        __syncthreads();
        #pragma unroll
        for (int mt = 0; mt < 2; ++mt)
            #pragma unroll
            for (int h = 0; h < 2; ++h) {
                uint4 v = *reinterpret_cast<const uint4*>(&lsbase[(w * 32 + mt * 16 + n16) * 72 + h * 32 + quad * 8]);
                *reinterpret_cast<uint4*>(sF + ((size_t)(tile0 + mt) * 8 + 2 * w + h) * 512 + lane * 8) = v;
            }
        return;
    }
    // pack_M: M_k = t[k,e]*W3[e,j] + W1[e,j]
    {
        const int HALF = B_ * K_ * 16 * 8 * 64;   // 1048576
        int gidx = (bid - 224) * 256 + tid;
        int isImg = gidx >= HALF;
        int idx = isImg ? gidx - HALF : gidx;
        const float* tP = isImg ? t_i : t_t;
        const float* W3 = (isImg ? i_m1_w : t_m1_w) + 2 * (size_t)E_ * E_;
        const float* W1 = isImg ? i_m1_w : t_m1_w;
        ushort_t* MF = isImg ? MF_i : MF_t;
        int lane = idx & 63;
        int kc = (idx >> 6) & 7;
        int nt = (idx >> 9) & 15;
        int bk = idx >> 13;
        int n = nt * 16 + (lane & 15);
        int e0 = kc * 32 + (lane >> 4) * 8;
        ushort_t out[8];
        #pragma unroll
        for (int j = 0; j < 8; ++j) {
            int e = e0 + j;
            float v = tP[(size_t)bk * E_ + e] * W3[(size_t)e * E_ + n] + W1[(size_t)e * E_ + n];
            out[j] = f2bf(v);
        }
        *reinterpret_cast<uint4*>(MF + (size_t)idx * 8) = *reinterpret_cast<uint4*>(out);
    }
}

// ===========================================================================
// Cross + edge via MFMA. grid (K=64, 48, B), k fastest. Writes Etmp[b][k][s].
// launch_bounds(256,4): ~128 total regs; (256,6) spilled in R6, (256,5)+mt=2
// was neutral-worse in R14 — this shape is the measured optimum.
// Accumulators MUST init to zero (R11). Epilogue gelu via raw v_exp_f32.
// ===========================================================================
__global__ __launch_bounds__(256, 4) void cross_mfma_kernel(
    const ushort_t* __restrict__ sF_t, const ushort_t* __restrict__ MF_t,
    const float* __restrict__ c2_t, const float* __restrict__ m2w_t,
    const float* __restrict__ m2b_t, const float* __restrict__ mask_t,
    float* __restrict__ Et,
    const ushort_t* __restrict__ sF_i, const ushort_t* __restrict__ MF_i,
    const float* __restrict__ c2_i, const float* __restrict__ m2w_i,
    const float* __restrict__ m2b_i, const float* __restrict__ mask_i,
    float* __restrict__ Ei)
{
    int k = blockIdx.x;
    int by = blockIdx.y;
    int isImg = by >= 32;
    int S = isImg ? SI_ : ST_;
    const ushort_t* sF = isImg ? sF_i : sF_t;
    const ushort_t* MF = isImg ? MF_i : MF_t;
    const float* c2P = isImg ? c2_i : c2_t;
    const float* m2w = isImg ? m2w_i : m2w_t;
    const float* m2b = isImg ? m2b_i : m2b_t;
    const float* mask = isImg ? mask_i : mask_t;
    float* Etmp = isImg ? Ei : Et;
    int s0 = (isImg ? by - 32 : by) * 64;
    int b = blockIdx.z;
    int tid = threadIdx.x;
    int w = tid >> 6, lane = tid & 63;
    int quad = lane >> 4, n16 = lane & 15;

    const ushort_t* aBase = sF + (size_t)(b * (S / 16) + (s0 >> 4)) * 4096;
    const ushort_t* bBase = MF + ((size_t)(b * K_ + k) * 16 + w * 4) * 4096;

    f32x4 acc[4][4];
    #pragma unroll
    for (int mt = 0; mt < 4; ++mt)
        #pragma unroll
        for (int nt = 0; nt < 4; ++nt)
            acc[mt][nt] = (f32x4){0.f, 0.f, 0.f, 0.f};

    #pragma unroll
    for (int kc = 0; kc < 8; ++kc) {
        bf16x8 bfr[4], af[4];
        #pragma unroll
        for (int nt = 0; nt < 4; ++nt)
            bfr[nt] = *reinterpret_cast<const bf16x8*>(bBase + (size_t)nt * 4096 + kc * 512 + lane * 8);
        #pragma unroll
        for (int mt = 0; mt < 4; ++mt)
            af[mt] = *reinterpret_cast<const bf16x8*>(aBase + (size_t)mt * 4096 + kc * 512 + lane * 8);
        #pragma unroll
        for (int mt = 0; mt < 4; ++mt)
            #pragma unroll
            for (int nt = 0; nt < 4; ++nt)
                acc[mt][nt] = __builtin_amdgcn_mfma_f32_16x16x32_bf16(af[mt], bfr[nt], acc[mt][nt], 0, 0, 0);
    }

    const float* c2v = c2P + (size_t)(b * K_ + k) * E_;
    float c2r[4], m2r[4];
    #pragma unroll
    for (int nt = 0; nt < 4; ++nt) {
        int col = w * 64 + nt * 16 + n16;
        c2r[nt] = c2v[col];
        m2r[nt] = m2w[col];
    }
    __shared__ float pPart[4][64];
    #pragma unroll
    for (int mt = 0; mt < 4; ++mt) {
        #pragma unroll
        for (int r = 0; r < 4; ++r) {
            float p = 0.f;
            #pragma unroll
            for (int nt = 0; nt < 4; ++nt) {
                float z = acc[mt][nt][r] + c2r[nt];
                // sigmoid-gelu: m2*z*sigmoid(1.702z); -1.702*log2(e) = -2.4554670
                float u = z * -2.4554670f;
                float t;
                asm("v_exp_f32 %0, %1" : "=v"(t) : "v"(u));
                float sg = __builtin_amdgcn_rcpf(1.0f + t);
                p = fmaf(m2r[nt] * z, sg, p);
            }
            p += __shfl_xor(p, 1, 64);
            p += __shfl_xor(p, 2, 64);
            p += __shfl_xor(p, 4, 64);
            p += __shfl_xor(p, 8, 64);
            if (n16 == 0) pPart[w][mt * 16 + quad * 4 + r] = p;
        }
    }
    __syncthreads();
    if (tid < 64) {
        float e = pPart[0][tid] + pPart[1][tid] + pPart[2][tid] + pPart[3][tid] + m2b[0];
        e = e / (1.0f + fabsf(e));
        int srow = s0 + tid;
        e *= mask[(size_t)b * S + srow];
        Etmp[(size_t)(b * K_ + k) * S + srow] = e;   // coalesced 256 B/block
    }
}

// ===========================================================================
// packE2: read Etmp[b][k][s] coalesced; write t2l/i2l, EF A-frags, rowsum.
// ===========================================================================
__global__ __launch_bounds__(256) void packE2_kernel(
    const float* __restrict__ Et, const float* __restrict__ Ei,
    float* __restrict__ t2l, float* __restrict__ i2l,
    ushort_t* __restrict__ EF_t, ushort_t* __restrict__ EF_i,
    float* __restrict__ rs_t, float* __restrict__ rs_i)
{
    __shared__ float tile[64][33];   // [k][s]
    int g = blockIdx.x;
    int isImg = g >= 128;
    const float* Esrc = isImg ? Ei : Et;
    float* dst = isImg ? i2l : t2l;
    ushort_t* EF = isImg ? EF_i : EF_t;
    float* rsum = isImg ? rs_i : rs_t;
    int chunk = isImg ? g - 128 : g;
    int S = isImg ? SI_ : ST_;
    int b = (chunk * 32) / S;
    int s0 = (chunk * 32) % S;
    int t = threadIdx.x;
    {
        int k = t >> 2, si = (t & 3) * 8;
        const float* p = Esrc + (size_t)(b * K_ + k) * S + s0 + si;
        *(float4*)&tile[k][si] = *(const float4*)p;
        *(float4*)&tile[k][si + 4] = *(const float4*)(p + 4);
    }
    __syncthreads();
    {
        int s = t >> 3, k0 = (t & 7) * 8;
        float o[8];
        #pragma unroll
        for (int j = 0; j < 8; ++j) o[j] = tile[k0 + j][s];
        float* p = dst + ((size_t)b * S + s0 + s) * K_ + k0;
        *(float4*)p = *(float4*)&o[0];
        *(float4*)(p + 4) = *(float4*)&o[4];
    }
    {
        int mt = t >> 6, lane = t & 63;
        int k = mt * 16 + (lane & 15);
        int sl0 = (lane >> 4) * 8;
        ushort_t o8[8];
        #pragma unroll
        for (int j = 0; j < 8; ++j)
            o8[j] = f2bf(tile[k][sl0 + j]);
        *reinterpret_cast<uint4*>(EF + (((size_t)chunk * 4 + mt) * 64 + lane) * 8) = *reinterpret_cast<uint4*>(o8);
    }
    if (t < 64) {
        float s = 0.f;
        #pragma unroll
        for (int j = 0; j < 32; ++j) s += tile[t][j];
        atomicAdd(&rsum[b * K_ + t], s);
    }
}

// ===========================================================================
// einsum via MFMA. grid (6, 8, 4): bz<2 text (b=bz), else image. nt=2/wave.
// 192 blocks = one clean wave over 256 CUs; 8 partials instead of 16.
// ===========================================================================
__global__ __launch_bounds__(256, 4) void einsum_mfma_kernel(
    const ushort_t* __restrict__ EF_t, const ushort_t* __restrict__ XhF_t,
    const ushort_t* __restrict__ XrF_t, float* __restrict__ PtG, float* __restrict__ PtR,
    const ushort_t* __restrict__ EF_i, const ushort_t* __restrict__ XhF_i,
    const ushort_t* __restrict__ XrF_i, float* __restrict__ PiG, float* __restrict__ PiR)
{
    int bz = blockIdx.z;
    int isImg = bz >= 2;
    int b = isImg ? bz - 2 : bz;
    int S = isImg ? SI_ : ST_;
    const ushort_t* EF = isImg ? EF_i : EF_t;
    const ushort_t* XhF = isImg ? XhF_i : XhF_t;
    const ushort_t* XrF = isImg ? XrF_i : XrF_t;
    float* PG = isImg ? PiG : PtG;
    float* PR = isImg ? PiR : PtR;
    int chunksPerBlock = isImg ? 4 : 8;

    int w = threadIdx.x >> 6, lane = threadIdx.x & 63;
    int quad = lane >> 4, n16 = lane & 15;
    int y = blockIdx.y;
    int nt0 = blockIdx.x * 8 + w * 2;
    size_t cb = (size_t)(b * S) / 32 + (size_t)y * chunksPerBlock;

    f32x4 aG[4][2], aR[4][2];
    #pragma unroll
    for (int mt = 0; mt < 4; ++mt)
        #pragma unroll
        for (int nt = 0; nt < 2; ++nt) {
            aG[mt][nt] = (f32x4){0.f, 0.f, 0.f, 0.f};
            aR[mt][nt] = (f32x4){0.f, 0.f, 0.f, 0.f};
        }

    for (int cc = 0; cc < chunksPerBlock; ++cc) {
        size_t c = cb + cc;
        bf16x8 af[4], bh[2], bx[2];
        #pragma unroll
        for (int mt = 0; mt < 4; ++mt)
            af[mt] = *reinterpret_cast<const bf16x8*>(EF + ((c * 4 + mt) * 64 + lane) * 8);
        #pragma unroll
        for (int nt = 0; nt < 2; ++nt) {
            bh[nt] = *reinterpret_cast<const bf16x8*>(XhF + ((c * 48 + nt0 + nt) * 64 + lane) * 8);
            bx[nt] = *reinterpret_cast<const bf16x8*>(XrF + ((c * 48 + nt0 + nt) * 64 + lane) * 8);
        }
        #pragma unroll
        for (int mt = 0; mt < 4; ++mt)
            #pragma unroll
            for (int nt = 0; nt < 2; ++nt) {
                aG[mt][nt] = __builtin_amdgcn_mfma_f32_16x16x32_bf16(af[mt], bh[nt], aG[mt][nt], 0, 0, 0);
                aR[mt][nt] = __builtin_amdgcn_mfma_f32_16x16x32_bf16(af[mt], bx[nt], aR[mt][nt], 0, 0, 0);
            }
    }
    #pragma unroll
    for (int mt = 0; mt < 4; ++mt)
        #pragma unroll
        for (int nt = 0; nt < 2; ++nt) {
            int d = (nt0 + nt) * 16 + n16;
            #pragma unroll
            for (int r = 0; r < 4; ++r) {
                int krow = mt * 16 + quad * 4 + r;
                size_t o = (((size_t)y * B_ + b) * K_ + krow) * D_ + d;
                PG[o] = aG[mt][nt][r];
                PR[o] = aR[mt][nt][r];
            }
        }
}

// ---------------------------------------------------------------------------
__global__ __launch_bounds__(256) void reduce_parts_kernel(
    const float* __restrict__ PtG, const float* __restrict__ PtR,
    const float* __restrict__ PiG, const float* __restrict__ PiR,
    float* __restrict__ Gt, float* __restrict__ Gi, float* __restrict__ Racc)
{
    const int BKD = B_ * K_ * D_;
    int idx = blockIdx.x * 256 + threadIdx.x;
    if (idx >= BKD) return;
    float gt = 0.f, gi = 0.f, r = 0.f;
    #pragma unroll
    for (int c = 0; c < 8; ++c) { gt += PtG[(size_t)c * BKD + idx]; r += PtR[(size_t)c * BKD + idx]; }
    #pragma unroll
    for (int c = 0; c < 8; ++c) { gi += PiG[(size_t)c * BKD + idx]; r += PiR[(size_t)c * BKD + idx]; }
    Gt[idx] = gt; Gi[idx] = gi; Racc[idx] = r;
}

// ---------------------------------------------------------------------------
// sgemm3: state_tmp = Gt@(g*tsp_w) + Gi@(g*isp_w), split-K atomics.
// grid flat 288, dyn LDS 8256 B
// ---------------------------------------------------------------------------
__global__ __launch_bounds__(256) void sgemm3_kernel(
    const float* __restrict__ Gt, const float* __restrict__ tsp_w, const float* __restrict__ tsn_g,
    const float* __restrict__ Gi, const float* __restrict__ isp_w, const float* __restrict__ isn_g,
    float* __restrict__ state_tmp)
{
    extern __shared__ __align__(16) char smem[];
    int f = blockIdx.x;
    int bx = f % 12, by = (f / 12) % 2, z = f / 24;  // z 0..11, nz0=6
    int cfg = (z >= 6) ? 1 : 0;
    int kz = cfg ? z - 6 : z;
    sgemm_body(smem, threadIdx.x,
               cfg ? Gi : Gt, cfg ? isp_w : tsp_w, cfg ? isn_g : tsn_g,
               nullptr, nullptr, nullptr, 0, state_tmp, kz, bx, by, D_, D_);
}

// ---------------------------------------------------------------------------
__global__ __launch_bounds__(256) void final_ln_kernel(
    const float* __restrict__ stateTmp, const float* __restrict__ Racc,
    const float* __restrict__ rs_t, const float* __restrict__ rs_i,
    const float* __restrict__ b_tspf, const float* __restrict__ b_ispf,
    const float* __restrict__ state_init, const float* __restrict__ value_init,
    const float* __restrict__ stn_g, const float* __restrict__ stn_b,
    const float* __restrict__ vn_g, const float* __restrict__ vn_b,
    float* __restrict__ outState, float* __restrict__ outValue)
{
    __shared__ float pre[D_];
    __shared__ float red[256];
    int idx = blockIdx.x;
    int row = idx & 127;
    int isVal = idx >> 7;
    int tid = threadIdx.x;
    if (!isVal) {
        float rt = rs_t[row], ri = rs_i[row];
        for (int d = tid; d < D_; d += 256)
            pre[d] = stateTmp[(size_t)row * D_ + d] + rt * b_tspf[d] + ri * b_ispf[d]
                   + state_init[(size_t)row * D_ + d];
    } else {
        for (int d = tid; d < D_; d += 256)
            pre[d] = Racc[(size_t)row * D_ + d] + value_init[(size_t)row * D_ + d];
    }
    __syncthreads();
    float s = 0.f;
    for (int d = tid; d < D_; d += 256) s += pre[d];
    red[tid] = s; __syncthreads();
    for (int off = 128; off > 0; off >>= 1) { if (tid < off) red[tid] += red[tid + off]; __syncthreads(); }
    float mu = red[0] / (float)D_;
    __syncthreads();
    float v = 0.f;
    for (int d = tid; d < D_; d += 256) { float t = pre[d] - mu; v += t * t; }
    red[tid] = v; __syncthreads();
    for (int off = 128; off > 0; off >>= 1) { if (tid < off) red[tid] += red[tid + off]; __syncthreads(); }
    float rstd = rsqrtf(red[0] / (float)D_ + EPS_LN);
    const float* g  = isVal ? vn_g : stn_g;
    const float* bb = isVal ? vn_b : stn_b;
    float* o = (isVal ? outValue : outState) + (size_t)row * D_;
    for (int d = tid; d < D_; d += 256) o[d] = (pre[d] - mu) * rstd * g[d] + bb[d];
}

// ---------------------------------------------------------------------------
extern "C" void kernel_launch(void* const* d_in, const int* in_sizes, int n_in,
                              void* d_out, int out_size, void* d_ws, size_t ws_size,
                              hipStream_t stream) {
    const float* text_values  = (const float*)d_in[0];
    const float* image_values = (const float*)d_in[1];
    const float* lstate_init  = (const float*)d_in[2];
    const float* lvalue_init  = (const float*)d_in[3];
    const float* text_mask    = (const float*)d_in[4];
    const float* image_mask   = (const float*)d_in[5];
    const float* t_sn_g = (const float*)d_in[6];
    const float* t_sn_b = (const float*)d_in[7];
    const float* t_tn_g = (const float*)d_in[8];
    const float* t_tn_b = (const float*)d_in[9];
    const float* t_su_w = (const float*)d_in[10];
    const float* t_su_b = (const float*)d_in[11];
    const float* t_tp_w = (const float*)d_in[12];
    const float* t_tp_b = (const float*)d_in[13];
    const float* t_m1_w = (const float*)d_in[14];
    const float* t_m1_b = (const float*)d_in[15];
    const float* t_m2_w = (const float*)d_in[16];
    const float* t_m2_b = (const float*)d_in[17];
    const float* i_sn_g = (const float*)d_in[18];
    const float* i_sn_b = (const float*)d_in[19];
    const float* i_tn_g = (const float*)d_in[20];
    const float* i_tn_b = (const float*)d_in[21];
    const float* i_su_w = (const float*)d_in[22];
    const float* i_su_b = (const float*)d_in[23];
    const float* i_tp_w = (const float*)d_in[24];
    const float* i_tp_b = (const float*)d_in[25];
    const float* i_m1_w = (const float*)d_in[26];
    const float* i_m1_b = (const float*)d_in[27];
    const float* i_m2_w = (const float*)d_in[28];
    const float* i_m2_b = (const float*)d_in[29];
    const float* tsn_g = (const float*)d_in[30];
    const float* tsn_b = (const float*)d_in[31];
    const float* isn_g = (const float*)d_in[32];
    const float* isn_b = (const float*)d_in[33];
    const float* stn_g = (const float*)d_in[34];
    const float* stn_b = (const float*)d_in[35];
    const float* vn_g  = (const float*)d_in[36];
    const float* vn_b  = (const float*)d_in[37];
    const float* tsp_w = (const float*)d_in[38];
    const float* tsp_b = (const float*)d_in[39];
    const float* isp_w = (const float*)d_in[40];
    const float* isp_b = (const float*)d_in[41];

    float* ws = (float*)d_ws;
    size_t o = 0;
    float* stats_mu = ws + o; o += 6272;
    float* stats_rs = ws + o; o += 6272;
    // --- zeroed block (contiguous) ---
    float* zeroBase = ws + o;
    float* b_su_t = ws + o; o += E_;
    float* b_su_i = ws + o; o += E_;
    float* b_tp_t = ws + o; o += E_;
    float* b_tp_i = ws + o; o += E_;
    float* b_tspf = ws + o; o += D_;
    float* b_ispf = ws + o; o += D_;
    float* t_t  = ws + o; o += (size_t)B_ * K_ * E_;
    float* t_i  = ws + o; o += (size_t)B_ * K_ * E_;
    float* c2_t = ws + o; o += (size_t)B_ * K_ * E_;
    float* c2_i = ws + o; o += (size_t)B_ * K_ * E_;
    float* state_tmp = ws + o; o += (size_t)B_ * K_ * D_;
    float* rs_t = ws + o; o += 128;
    float* rs_i = ws + o; o += 128;
    size_t zeroFloats = (size_t)(4 * E_ + 2 * D_ + 4 * B_ * K_ * E_ + B_ * K_ * D_ + 256);
    // --- end zeroed block ---
    float* Etmp_t = ws + o; o += (size_t)B_ * K_ * ST_;
    float* Etmp_i = ws + o; o += (size_t)B_ * K_ * SI_;
    ushort_t* AF_t = (ushort_t*)(ws + o); o += (size_t)B_ * ST_ * D_ / 2;
    ushort_t* AF_i = (ushort_t*)(ws + o); o += (size_t)B_ * SI_ * D_ / 2;
    ushort_t* WsuF_t = (ushort_t*)(ws + o); o += (size_t)D_ * E_ / 2;
    ushort_t* WsuF_i = (ushort_t*)(ws + o); o += (size_t)D_ * E_ / 2;
    ushort_t* sF_t = (ushort_t*)(ws + o); o += (size_t)B_ * ST_ * E_ / 2;
    ushort_t* sF_i = (ushort_t*)(ws + o); o += (size_t)B_ * SI_ * E_ / 2;
    ushort_t* MF_t = (ushort_t*)(ws + o); o += (size_t)B_ * K_ * E_ * E_ / 2;
    ushort_t* MF_i = (ushort_t*)(ws + o); o += (size_t)B_ * K_ * E_ * E_ / 2;
    ushort_t* XhF_t = (ushort_t*)(ws + o); o += (size_t)B_ * ST_ * D_ / 2;
    ushort_t* XhF_i = (ushort_t*)(ws + o); o += (size_t)B_ * SI_ * D_ / 2;
    ushort_t* XrF_t = (ushort_t*)(ws + o); o += (size_t)B_ * ST_ * D_ / 2;
    ushort_t* XrF_i = (ushort_t*)(ws + o); o += (size_t)B_ * SI_ * D_ / 2;
    ushort_t* EF_t  = (ushort_t*)(ws + o); o += (size_t)B_ * ST_ * K_ / 2;
    ushort_t* EF_i  = (ushort_t*)(ws + o); o += (size_t)B_ * SI_ * K_ / 2;
    const int BKD = B_ * K_ * D_;
    float* PtG = ws + o; o += (size_t)8 * BKD;
    float* PtR = ws + o; o += (size_t)8 * BKD;
    float* PiG = ws + o; o += (size_t)8 * BKD;
    float* PiR = ws + o; o += (size_t)8 * BKD;
    float* Gt   = ws + o; o += BKD;
    float* Gi   = ws + o; o += BKD;
    float* Racc = ws + o; o += BKD;

    float* outState = (float*)d_out;
    float* outValue = (float*)d_out + (size_t)B_ * K_ * D_;
    float* t2l = (float*)d_out + 2 * (size_t)B_ * K_ * D_;
    float* i2l = t2l + (size_t)B_ * ST_ * K_;

    hipMemsetAsync(zeroBase, 0, zeroFloats * sizeof(float), stream);

    prelude_kernel<<<2624, 256, 1024, stream>>>(
        text_values, image_values, lvalue_init, stats_mu, stats_rs,
        t_sn_b, t_su_w, t_su_b, b_su_t,
        i_sn_b, i_su_w, i_su_b, b_su_i,
        t_tn_b, t_tp_w, t_tp_b, b_tp_t,
        i_tn_b, i_tp_w, i_tp_b, b_tp_i,
        tsn_b, tsp_w, tsp_b, b_tspf,
        isn_b, isp_w, isp_b, b_ispf,
        t_su_w, t_sn_g, WsuF_t,
        i_su_w, i_sn_g, WsuF_i);

    stage2_kernel<<<1248, 256, 17152, stream>>>(
        text_values, image_values, stats_mu, stats_rs,
        XrF_t, XhF_t, AF_t, XrF_i, XhF_i, AF_i,
        lvalue_init,
        t_tp_w, t_tn_g, b_tp_t, t_t,
        i_tp_w, i_tn_g, b_tp_i, t_i);

    stage3_kernel<<<8416, 256, 18432, stream>>>(
        t_t, t_i, t_m1_w, t_m1_b, i_m1_w, i_m1_b, c2_t, c2_i,
        AF_t, WsuF_t, b_su_t, sF_t,
        AF_i, WsuF_i, b_su_i, sF_i,
        MF_t, MF_i);

    cross_mfma_kernel<<<dim3(K_, 48, B_), 256, 0, stream>>>(
        sF_t, MF_t, c2_t, t_m2_w, t_m2_b, text_mask, Etmp_t,
        sF_i, MF_i, c2_i, i_m2_w, i_m2_b, image_mask, Etmp_i);

    packE2_kernel<<<192, 256, 0, stream>>>(
        Etmp_t, Etmp_i, t2l, i2l, EF_t, EF_i, rs_t, rs_i);

    einsum_mfma_kernel<<<dim3(6, 8, 4), 256, 0, stream>>>(
        EF_t, XhF_t, XrF_t, PtG, PtR,
        EF_i, XhF_i, XrF_i, PiG, PiR);

    reduce_parts_kernel<<<(BKD + 255) / 256, 256, 0, stream>>>(PtG, PtR, PiG, PiR, Gt, Gi, Racc);

    sgemm3_kernel<<<288, 256, 8256, stream>>>(
        Gt, tsp_w, tsn_g, Gi, isp_w, isn_g, state_tmp);

    final_ln_kernel<<<2 * B_ * K_, 256, 0, stream>>>(
        state_tmp, Racc, rs_t, rs_i, b_tspf, b_ispf,
        lstate_init, lvalue_init, stn_g, stn_b, vn_g, vn_b, outState, outValue);
}